// Round 1
// baseline (1160.826 us; speedup 1.0000x reference)
//
#include <hip/hip_runtime.h>
#include <hip/hip_bf16.h>

// Problem constants (fixed by the reference)
static constexpr int N_NODES = 50000;
static constexpr int N_EDGE  = 1000000;
static constexpr int IN_D    = 256;
static constexpr int HID_D   = 128;
static constexpr int OUT_D   = 64;
static constexpr int R_REL   = 2;

// ---------------- fp32 tiled GEMM: C[M,Nn] = A[M,K] @ B (+bias) ----------------
// B row-major (K,Nn) when BT=false; B row-major (Nn,K) when BT=true (i.e. A @ B^T).
// Batched over blockIdx.z with strides sB, sC (A shared across batch).
#define BM 64
#define BN 64
#define BK 16

template<bool BT, bool BIAS>
__global__ __launch_bounds__(256) void gemm_k(
    const float* __restrict__ A, const float* __restrict__ B,
    const float* __restrict__ bias, float* __restrict__ C,
    int M, int K, int Nn, long sB, long sC)
{
    const float* Bp = B + (long)blockIdx.z * sB;
    float* Cp = C + (long)blockIdx.z * sC;
    const int bm = blockIdx.y * BM;
    const int bn = blockIdx.x * BN;

    __shared__ float As[BK][BM + 4];   // +4 keeps float4 alignment, breaks pow2 stride
    __shared__ float Bs[BK][BN + 4];

    const int tid = threadIdx.x;
    const int tx = tid & 15;    // n-dir, 4 cols each
    const int ty = tid >> 4;    // m-dir, 4 rows each

    float acc[4][4] = {};

    for (int k0 = 0; k0 < K; k0 += BK) {
        // stage A tile (BM x BK), stored transposed As[k][m]
        {
            const int r = tid >> 2;          // 0..63 (m)
            const int c = (tid & 3) << 2;    // 0,4,8,12 (k)
            float4 v = make_float4(0.f, 0.f, 0.f, 0.f);
            const int m = bm + r;
            if (m < M) v = *(const float4*)(A + (long)m * K + k0 + c);
            As[c + 0][r] = v.x; As[c + 1][r] = v.y;
            As[c + 2][r] = v.z; As[c + 3][r] = v.w;
        }
        // stage B tile (BK x BN) as Bs[k][n]
        if (!BT) {
            const int r = tid >> 4;          // 0..15 (k)
            const int c = (tid & 15) << 2;   // 0..60 (n)
            const int n = bn + c;
            float4 v = make_float4(0.f, 0.f, 0.f, 0.f);
            if (n < Nn) v = *(const float4*)(Bp + (long)(k0 + r) * Nn + n);
            Bs[r][c] = v.x; Bs[r][c + 1] = v.y; Bs[r][c + 2] = v.z; Bs[r][c + 3] = v.w;
        } else {
            const int r = tid >> 2;          // 0..63 (n local)
            const int c = (tid & 3) << 2;    // 0,4,8,12 (k)
            const int n = bn + r;
            float4 v = make_float4(0.f, 0.f, 0.f, 0.f);
            if (n < Nn) v = *(const float4*)(Bp + (long)n * K + k0 + c);
            Bs[c + 0][r] = v.x; Bs[c + 1][r] = v.y;
            Bs[c + 2][r] = v.z; Bs[c + 3][r] = v.w;
        }
        __syncthreads();

#pragma unroll
        for (int k = 0; k < BK; ++k) {
            const float4 a = *(const float4*)&As[k][ty << 2];
            const float4 b = *(const float4*)&Bs[k][tx << 2];
            acc[0][0] = fmaf(a.x, b.x, acc[0][0]);
            acc[0][1] = fmaf(a.x, b.y, acc[0][1]);
            acc[0][2] = fmaf(a.x, b.z, acc[0][2]);
            acc[0][3] = fmaf(a.x, b.w, acc[0][3]);
            acc[1][0] = fmaf(a.y, b.x, acc[1][0]);
            acc[1][1] = fmaf(a.y, b.y, acc[1][1]);
            acc[1][2] = fmaf(a.y, b.z, acc[1][2]);
            acc[1][3] = fmaf(a.y, b.w, acc[1][3]);
            acc[2][0] = fmaf(a.z, b.x, acc[2][0]);
            acc[2][1] = fmaf(a.z, b.y, acc[2][1]);
            acc[2][2] = fmaf(a.z, b.z, acc[2][2]);
            acc[2][3] = fmaf(a.z, b.w, acc[2][3]);
            acc[3][0] = fmaf(a.w, b.x, acc[3][0]);
            acc[3][1] = fmaf(a.w, b.y, acc[3][1]);
            acc[3][2] = fmaf(a.w, b.z, acc[3][2]);
            acc[3][3] = fmaf(a.w, b.w, acc[3][3]);
        }
        __syncthreads();
    }

#pragma unroll
    for (int mi = 0; mi < 4; ++mi) {
        const int m = bm + (ty << 2) + mi;
        if (m >= M) continue;
        float* crow = Cp + (long)m * Nn;
#pragma unroll
        for (int ni = 0; ni < 4; ++ni) {
            const int n = bn + (tx << 2) + ni;
            if (n < Nn) {
                float v = acc[mi][ni];
                if (BIAS) v += bias[n];
                crow[n] = v;
            }
        }
    }
}

// ---------------- per-(relation,node) q/k dot products: one wave per row -------
__global__ __launch_bounds__(256) void dots_k(
    const float* __restrict__ proj, const float* __restrict__ q,
    const float* __restrict__ k, float* __restrict__ qd, float* __restrict__ kd,
    int total, int D)
{
    const int wid = (int)((blockIdx.x * (long)blockDim.x + threadIdx.x) >> 6);
    const int lane = threadIdx.x & 63;
    if (wid >= total) return;
    const float* row = proj + (long)wid * D;
    float sq = 0.f, sk = 0.f;
    for (int i = lane; i < D; i += 64) {
        const float v = row[i];
        sq = fmaf(v, q[i], sq);
        sk = fmaf(v, k[i], sk);
    }
#pragma unroll
    for (int off = 32; off; off >>= 1) {
        sq += __shfl_down(sq, off);
        sk += __shfl_down(sk, off);
    }
    if (lane == 0) { qd[wid] = sq; kd[wid] = sk; }
}

// ---------------- per-edge score: exp(leaky_relu(qd[dst]+kd[src])) + denom -----
__global__ __launch_bounds__(256) void edge_score_k(
    const int* __restrict__ srcv, const int* __restrict__ dstv,
    const int* __restrict__ et, const float* __restrict__ qd,
    const float* __restrict__ kd, float* __restrict__ ex_out,
    float* __restrict__ denom, int E, int Nn)
{
    const int e = blockIdx.x * blockDim.x + threadIdx.x;
    if (e >= E) return;
    const int t = et[e];
    const int s = srcv[e];
    const int d = dstv[e];
    float a = qd[t * Nn + d] + kd[t * Nn + s];
    a = a > 0.f ? a : 0.2f * a;            // leaky_relu, slope 0.2
    const float ev = expf(a);              // softmax is shift-invariant; |a| small
    ex_out[e] = ev;
    atomicAdd(&denom[d], ev);
}

// ---------------- normalize attention in place ---------------------------------
__global__ __launch_bounds__(256) void norm_att_k(
    float* __restrict__ att, const float* __restrict__ denom,
    const int* __restrict__ dstv, int E)
{
    const int e = blockIdx.x * blockDim.x + threadIdx.x;
    if (e >= E) return;
    att[e] = att[e] / (denom[dstv[e]] + 1e-16f);
}

// ---------------- edge aggregation: hout[dst] += att * proj[t,src] (atomic) ----
__global__ __launch_bounds__(256) void edge_aggr_k(
    const int* __restrict__ srcv, const int* __restrict__ dstv,
    const int* __restrict__ et, const float* __restrict__ proj,
    const float* __restrict__ att, float* __restrict__ hout,
    int E, int lgD, int Nn)
{
    const long idx = blockIdx.x * (long)blockDim.x + threadIdx.x;
    const int D = 1 << lgD;
    if (idx >= (long)E << lgD) return;
    const int e = (int)(idx >> lgD);
    const int h = (int)(idx & (D - 1));
    const int t = et[e];
    const int s = srcv[e];
    const int d = dstv[e];
    const float w = att[e];
    const float v = proj[((long)t * Nn + s) * D + h];
    atomicAdd(&hout[(long)d * D + h], w * v);
}

// ---------------- elu in place --------------------------------------------------
__global__ __launch_bounds__(256) void elu_k(float* __restrict__ x, long n)
{
    const long i = blockIdx.x * (long)blockDim.x + threadIdx.x;
    if (i >= n) return;
    const float v = x[i];
    x[i] = v > 0.f ? v : expm1f(v);
}

extern "C" void kernel_launch(void* const* d_in, const int* in_sizes, int n_in,
                              void* d_out, int out_size, void* d_ws, size_t ws_size,
                              hipStream_t stream)
{
    const float* features = (const float*)d_in[0];
    const int*   eidx     = (const int*)d_in[1];
    const int*   etype    = (const int*)d_in[2];
    const float* W1       = (const float*)d_in[3];
    const float* q1       = (const float*)d_in[4];
    const float* k1       = (const float*)d_in[5];
    const float* W2       = (const float*)d_in[6];
    const float* q2       = (const float*)d_in[7];
    const float* k2       = (const float*)d_in[8];
    const float* dw1      = (const float*)d_in[9];
    const float* db1      = (const float*)d_in[10];
    const float* dw2      = (const float*)d_in[11];
    const float* db2      = (const float*)d_in[12];

    const int* srcv = eidx;            // edge_index[0]
    const int* dstv = eidx + N_EDGE;   // edge_index[1]

    float* out_h2 = (float*)d_out;                         // N x OUT
    float* out_h3 = out_h2 + (long)N_NODES * OUT_D;        // N x IN
    float* att1   = out_h3 + (long)N_NODES * IN_D;         // E
    float* att2   = att1 + N_EDGE;                         // E

    float* ws    = (float*)d_ws;
    float* proj1 = ws;                                     // R*N*HID
    float* proj2 = proj1 + (long)R_REL * N_NODES * HID_D;  // R*N*OUT
    float* h1    = proj2 + (long)R_REL * N_NODES * OUT_D;  // N*HID
    float* qd1   = h1 + (long)N_NODES * HID_D;             // R*N
    float* kd1   = qd1 + R_REL * N_NODES;
    float* qd2   = kd1 + R_REL * N_NODES;
    float* kd2   = qd2 + R_REL * N_NODES;
    float* den1  = kd2 + R_REL * N_NODES;                  // N
    float* den2  = den1 + N_NODES;                         // N
    float* hmid  = proj1;  // reuse: proj1 dead after layer-1 aggregation

    hipMemsetAsync(h1, 0, sizeof(float) * (size_t)N_NODES * HID_D, stream);
    hipMemsetAsync(out_h2, 0, sizeof(float) * (size_t)N_NODES * OUT_D, stream);
    hipMemsetAsync(den1, 0, sizeof(float) * N_NODES, stream);
    hipMemsetAsync(den2, 0, sizeof(float) * N_NODES, stream);

    // ---- layer 1 ----
    {
        dim3 g((HID_D + BN - 1) / BN, (N_NODES + BM - 1) / BM, R_REL);
        gemm_k<false, false><<<g, 256, 0, stream>>>(features, W1, nullptr, proj1,
            N_NODES, IN_D, HID_D, (long)IN_D * HID_D, (long)N_NODES * HID_D);
    }
    dots_k<<<(R_REL * N_NODES * 64 + 255) / 256, 256, 0, stream>>>(
        proj1, q1, k1, qd1, kd1, R_REL * N_NODES, HID_D);
    edge_score_k<<<(N_EDGE + 255) / 256, 256, 0, stream>>>(
        srcv, dstv, etype, qd1, kd1, att1, den1, N_EDGE, N_NODES);
    norm_att_k<<<(N_EDGE + 255) / 256, 256, 0, stream>>>(att1, den1, dstv, N_EDGE);
    {
        const long tot = (long)N_EDGE * HID_D;
        edge_aggr_k<<<(int)((tot + 255) / 256), 256, 0, stream>>>(
            srcv, dstv, etype, proj1, att1, h1, N_EDGE, 7, N_NODES);
    }
    elu_k<<<(int)(((long)N_NODES * HID_D + 255) / 256), 256, 0, stream>>>(
        h1, (long)N_NODES * HID_D);

    // ---- layer 2 ----
    {
        dim3 g((OUT_D + BN - 1) / BN, (N_NODES + BM - 1) / BM, R_REL);
        gemm_k<false, false><<<g, 256, 0, stream>>>(h1, W2, nullptr, proj2,
            N_NODES, HID_D, OUT_D, (long)HID_D * OUT_D, (long)N_NODES * OUT_D);
    }
    dots_k<<<(R_REL * N_NODES * 64 + 255) / 256, 256, 0, stream>>>(
        proj2, q2, k2, qd2, kd2, R_REL * N_NODES, OUT_D);
    edge_score_k<<<(N_EDGE + 255) / 256, 256, 0, stream>>>(
        srcv, dstv, etype, qd2, kd2, att2, den2, N_EDGE, N_NODES);
    norm_att_k<<<(N_EDGE + 255) / 256, 256, 0, stream>>>(att2, den2, dstv, N_EDGE);
    {
        const long tot = (long)N_EDGE * OUT_D;
        edge_aggr_k<<<(int)((tot + 255) / 256), 256, 0, stream>>>(
            srcv, dstv, etype, proj2, att2, out_h2, N_EDGE, 6, N_NODES);
    }
    elu_k<<<(int)(((long)N_NODES * OUT_D + 255) / 256), 256, 0, stream>>>(
        out_h2, (long)N_NODES * OUT_D);

    // ---- decoder ----
    {
        dim3 g((HID_D + BN - 1) / BN, (N_NODES + BM - 1) / BM, 1);
        gemm_k<true, true><<<g, 256, 0, stream>>>(out_h2, dw1, db1, hmid,
            N_NODES, OUT_D, HID_D, 0, 0);
    }
    {
        dim3 g((IN_D + BN - 1) / BN, (N_NODES + BM - 1) / BM, 1);
        gemm_k<true, true><<<g, 256, 0, stream>>>(hmid, dw2, db2, out_h3,
            N_NODES, HID_D, IN_D, 0, 0);
    }
}

// Round 2
// 719.397 us; speedup vs baseline: 1.6136x; 1.6136x over previous
//
#include <hip/hip_runtime.h>
#include <hip/hip_bf16.h>

static constexpr int N_NODES = 50000;
static constexpr int N_EDGE  = 1000000;
static constexpr int IN_D    = 256;
static constexpr int HID_D   = 128;
static constexpr int OUT_D   = 64;
static constexpr int R_REL   = 2;

// ---------------- fp32 tiled GEMM: C[M,Nn] = A[M,K] @ B (+bias) ----------------
#define BM 64
#define BN 64
#define BK 16

template<bool BT, bool BIAS>
__global__ __launch_bounds__(256) void gemm_k(
    const float* __restrict__ A, const float* __restrict__ B,
    const float* __restrict__ bias, float* __restrict__ C,
    int M, int K, int Nn, long sB, long sC)
{
    const float* Bp = B + (long)blockIdx.z * sB;
    float* Cp = C + (long)blockIdx.z * sC;
    const int bm = blockIdx.y * BM;
    const int bn = blockIdx.x * BN;

    __shared__ float As[BK][BM + 4];
    __shared__ float Bs[BK][BN + 4];

    const int tid = threadIdx.x;
    const int tx = tid & 15;
    const int ty = tid >> 4;

    float acc[4][4] = {};

    for (int k0 = 0; k0 < K; k0 += BK) {
        {
            const int r = tid >> 2;
            const int c = (tid & 3) << 2;
            float4 v = make_float4(0.f, 0.f, 0.f, 0.f);
            const int m = bm + r;
            if (m < M) v = *(const float4*)(A + (long)m * K + k0 + c);
            As[c + 0][r] = v.x; As[c + 1][r] = v.y;
            As[c + 2][r] = v.z; As[c + 3][r] = v.w;
        }
        if (!BT) {
            const int r = tid >> 4;
            const int c = (tid & 15) << 2;
            const int n = bn + c;
            float4 v = make_float4(0.f, 0.f, 0.f, 0.f);
            if (n < Nn) v = *(const float4*)(Bp + (long)(k0 + r) * Nn + n);
            Bs[r][c] = v.x; Bs[r][c + 1] = v.y; Bs[r][c + 2] = v.z; Bs[r][c + 3] = v.w;
        } else {
            const int r = tid >> 2;
            const int c = (tid & 3) << 2;
            const int n = bn + r;
            float4 v = make_float4(0.f, 0.f, 0.f, 0.f);
            if (n < Nn) v = *(const float4*)(Bp + (long)n * K + k0 + c);
            Bs[c + 0][r] = v.x; Bs[c + 1][r] = v.y;
            Bs[c + 2][r] = v.z; Bs[c + 3][r] = v.w;
        }
        __syncthreads();

#pragma unroll
        for (int k = 0; k < BK; ++k) {
            const float4 a = *(const float4*)&As[k][ty << 2];
            const float4 b = *(const float4*)&Bs[k][tx << 2];
            acc[0][0] = fmaf(a.x, b.x, acc[0][0]);
            acc[0][1] = fmaf(a.x, b.y, acc[0][1]);
            acc[0][2] = fmaf(a.x, b.z, acc[0][2]);
            acc[0][3] = fmaf(a.x, b.w, acc[0][3]);
            acc[1][0] = fmaf(a.y, b.x, acc[1][0]);
            acc[1][1] = fmaf(a.y, b.y, acc[1][1]);
            acc[1][2] = fmaf(a.y, b.z, acc[1][2]);
            acc[1][3] = fmaf(a.y, b.w, acc[1][3]);
            acc[2][0] = fmaf(a.z, b.x, acc[2][0]);
            acc[2][1] = fmaf(a.z, b.y, acc[2][1]);
            acc[2][2] = fmaf(a.z, b.z, acc[2][2]);
            acc[2][3] = fmaf(a.z, b.w, acc[2][3]);
            acc[3][0] = fmaf(a.w, b.x, acc[3][0]);
            acc[3][1] = fmaf(a.w, b.y, acc[3][1]);
            acc[3][2] = fmaf(a.w, b.z, acc[3][2]);
            acc[3][3] = fmaf(a.w, b.w, acc[3][3]);
        }
        __syncthreads();
    }

#pragma unroll
    for (int mi = 0; mi < 4; ++mi) {
        const int m = bm + (ty << 2) + mi;
        if (m >= M) continue;
        float* crow = Cp + (long)m * Nn;
#pragma unroll
        for (int ni = 0; ni < 4; ++ni) {
            const int n = bn + (tx << 2) + ni;
            if (n < Nn) {
                float v = acc[mi][ni];
                if (BIAS) v += bias[n];
                crow[n] = v;
            }
        }
    }
}

// ---------------- per-(relation,node) q/k dot products -------------------------
__global__ __launch_bounds__(256) void dots_k(
    const float* __restrict__ proj, const float* __restrict__ q,
    const float* __restrict__ k, float* __restrict__ qd, float* __restrict__ kd,
    int total, int D)
{
    const int wid = (int)((blockIdx.x * (long)blockDim.x + threadIdx.x) >> 6);
    const int lane = threadIdx.x & 63;
    if (wid >= total) return;
    const float* row = proj + (long)wid * D;
    float sq = 0.f, sk = 0.f;
    for (int i = lane; i < D; i += 64) {
        const float v = row[i];
        sq = fmaf(v, q[i], sq);
        sk = fmaf(v, k[i], sk);
    }
#pragma unroll
    for (int off = 32; off; off >>= 1) {
        sq += __shfl_down(sq, off);
        sk += __shfl_down(sk, off);
    }
    if (lane == 0) { qd[wid] = sq; kd[wid] = sk; }
}

// ---------------- CSR build: histogram, scan, scatter ---------------------------
__global__ __launch_bounds__(256) void hist_k(
    const int* __restrict__ dstv, int* __restrict__ cnt, int E)
{
    const int e = blockIdx.x * blockDim.x + threadIdx.x;
    if (e >= E) return;
    atomicAdd(&cnt[dstv[e]], 1);
}

// single-block exclusive scan over n counters; offs[n] = total; cursor = copy
__global__ __launch_bounds__(1024) void scan_k(
    const int* __restrict__ cnt, int* __restrict__ offs,
    int* __restrict__ cursor, int n)
{
    __shared__ int buf[1024];
    __shared__ int carry;
    const int tid = threadIdx.x;
    if (tid == 0) carry = 0;
    __syncthreads();
    for (int base = 0; base < n; base += 1024) {
        const int i = base + tid;
        const int v = (i < n) ? cnt[i] : 0;
        buf[tid] = v;
        __syncthreads();
        for (int off = 1; off < 1024; off <<= 1) {
            int t = (tid >= off) ? buf[tid - off] : 0;
            __syncthreads();
            buf[tid] += t;
            __syncthreads();
        }
        const int excl = buf[tid] - v + carry;
        if (i < n) { offs[i] = excl; cursor[i] = excl; }
        __syncthreads();
        if (tid == 1023) carry += buf[1023];
        __syncthreads();
    }
    if (tid == 0) offs[n] = carry;
}

// scatter edges into dst-sorted order; pack (type<<16)|src (src < 65536)
__global__ __launch_bounds__(256) void scatter_k(
    const int* __restrict__ srcv, const int* __restrict__ dstv,
    const int* __restrict__ et, int* __restrict__ cursor,
    int* __restrict__ spack, int* __restrict__ sperm, int E)
{
    const int e = blockIdx.x * blockDim.x + threadIdx.x;
    if (e >= E) return;
    const int d = dstv[e];
    const int pos = atomicAdd(&cursor[d], 1);
    spack[pos] = (et[e] << 16) | srcv[e];
    sperm[pos] = e;
}

// ---------------- fused per-node softmax + aggregation + ELU -------------------
// one wave per dst node; D = 1<<LGD (64 or 128)
template<int LGD>
__global__ __launch_bounds__(256) void aggr_csr_k(
    const int* __restrict__ offs, const int* __restrict__ spack,
    const int* __restrict__ sperm, const float* __restrict__ qd,
    const float* __restrict__ kd, const float* __restrict__ proj,
    float* __restrict__ att_out, float* __restrict__ out, int Nn)
{
    const int d = blockIdx.x * 4 + (threadIdx.x >> 6);
    const int lane = threadIdx.x & 63;
    if (d >= Nn) return;

    const int beg = offs[d], end = offs[d + 1];
    const float qd0 = qd[d];
    const float qd1 = qd[Nn + d];

    // pass 1: softmax denominator (shift-invariant: skip max subtraction)
    float exsum = 0.f;
    for (int b = beg; b < end; b += 64) {
        const int i = b + lane;
        float ex = 0.f;
        if (i < end) {
            const int p = spack[i];
            const int s = p & 0xFFFF;
            const int t = p >> 16;
            float a = (t ? qd1 : qd0) + kd[t * Nn + s];
            a = a > 0.f ? a : 0.2f * a;
            ex = expf(a);
        }
#pragma unroll
        for (int off = 32; off; off >>= 1) ex += __shfl_xor(ex, off);
        exsum += ex;  // uniform across lanes
    }
    const float inv_den = 1.f / (exsum + 1e-16f);

    // pass 2: recompute scores, write att, accumulate att * proj[t,src]
    float acc0 = 0.f, acc1 = 0.f;
    for (int b = beg; b < end; b += 64) {
        const int i = b + lane;
        float av = 0.f;
        int sp = 0;
        if (i < end) {
            sp = spack[i];
            const int s = sp & 0xFFFF;
            const int t = sp >> 16;
            float a = (t ? qd1 : qd0) + kd[t * Nn + s];
            a = a > 0.f ? a : 0.2f * a;
            av = expf(a) * inv_den;
            att_out[sperm[i]] = av;
        }
        const int cnt = min(64, end - b);
        for (int j = 0; j < cnt; ++j) {
            const float aj = __shfl(av, j);
            const int spj = __shfl(sp, j);
            const int sj = spj & 0xFFFF;
            const int tj = spj >> 16;
            const float* row = proj + (((long)tj * Nn + sj) << LGD);
            acc0 = fmaf(aj, row[lane], acc0);
            if (LGD == 7) acc1 = fmaf(aj, row[lane + 64], acc1);
        }
    }

    // epilogue: ELU + streaming store
    float v0 = acc0 > 0.f ? acc0 : expm1f(acc0);
    out[((long)d << LGD) + lane] = v0;
    if (LGD == 7) {
        float v1 = acc1 > 0.f ? acc1 : expm1f(acc1);
        out[((long)d << LGD) + 64 + lane] = v1;
    }
}

extern "C" void kernel_launch(void* const* d_in, const int* in_sizes, int n_in,
                              void* d_out, int out_size, void* d_ws, size_t ws_size,
                              hipStream_t stream)
{
    const float* features = (const float*)d_in[0];
    const int*   eidx     = (const int*)d_in[1];
    const int*   etype    = (const int*)d_in[2];
    const float* W1       = (const float*)d_in[3];
    const float* q1       = (const float*)d_in[4];
    const float* k1       = (const float*)d_in[5];
    const float* W2       = (const float*)d_in[6];
    const float* q2       = (const float*)d_in[7];
    const float* k2       = (const float*)d_in[8];
    const float* dw1      = (const float*)d_in[9];
    const float* db1      = (const float*)d_in[10];
    const float* dw2      = (const float*)d_in[11];
    const float* db2      = (const float*)d_in[12];

    const int* srcv = eidx;
    const int* dstv = eidx + N_EDGE;

    float* out_h2 = (float*)d_out;
    float* out_h3 = out_h2 + (long)N_NODES * OUT_D;
    float* att1   = out_h3 + (long)N_NODES * IN_D;
    float* att2   = att1 + N_EDGE;

    float* ws    = (float*)d_ws;
    float* proj1 = ws;                                     // R*N*HID
    float* proj2 = proj1 + (long)R_REL * N_NODES * HID_D;  // R*N*OUT
    float* h1    = proj2 + (long)R_REL * N_NODES * OUT_D;  // N*HID
    float* qd1   = h1 + (long)N_NODES * HID_D;
    float* kd1   = qd1 + R_REL * N_NODES;
    float* qd2   = kd1 + R_REL * N_NODES;
    float* kd2   = qd2 + R_REL * N_NODES;
    int*   cnt    = (int*)(kd2 + R_REL * N_NODES);         // N
    int*   offs   = cnt + N_NODES;                         // N+1
    int*   cursor = offs + N_NODES + 1;                    // N
    int*   spack  = cursor + N_NODES;                      // E
    int*   sperm  = spack + N_EDGE;                        // E
    float* hmid   = proj1;   // reuse after layer-1 aggregation

    // ---- CSR build (shared by both layers) ----
    hipMemsetAsync(cnt, 0, sizeof(int) * N_NODES, stream);
    hist_k<<<(N_EDGE + 255) / 256, 256, 0, stream>>>(dstv, cnt, N_EDGE);
    scan_k<<<1, 1024, 0, stream>>>(cnt, offs, cursor, N_NODES);
    scatter_k<<<(N_EDGE + 255) / 256, 256, 0, stream>>>(
        srcv, dstv, etype, cursor, spack, sperm, N_EDGE);

    // ---- layer 1 ----
    {
        dim3 g((HID_D + BN - 1) / BN, (N_NODES + BM - 1) / BM, R_REL);
        gemm_k<false, false><<<g, 256, 0, stream>>>(features, W1, nullptr, proj1,
            N_NODES, IN_D, HID_D, (long)IN_D * HID_D, (long)N_NODES * HID_D);
    }
    dots_k<<<(R_REL * N_NODES * 64 + 255) / 256, 256, 0, stream>>>(
        proj1, q1, k1, qd1, kd1, R_REL * N_NODES, HID_D);
    aggr_csr_k<7><<<(N_NODES + 3) / 4, 256, 0, stream>>>(
        offs, spack, sperm, qd1, kd1, proj1, att1, h1, N_NODES);

    // ---- layer 2 ----
    {
        dim3 g((OUT_D + BN - 1) / BN, (N_NODES + BM - 1) / BM, R_REL);
        gemm_k<false, false><<<g, 256, 0, stream>>>(h1, W2, nullptr, proj2,
            N_NODES, HID_D, OUT_D, (long)HID_D * OUT_D, (long)N_NODES * OUT_D);
    }
    dots_k<<<(R_REL * N_NODES * 64 + 255) / 256, 256, 0, stream>>>(
        proj2, q2, k2, qd2, kd2, R_REL * N_NODES, OUT_D);
    aggr_csr_k<6><<<(N_NODES + 3) / 4, 256, 0, stream>>>(
        offs, spack, sperm, qd2, kd2, proj2, att2, out_h2, N_NODES);

    // ---- decoder ----
    {
        dim3 g((HID_D + BN - 1) / BN, (N_NODES + BM - 1) / BM, 1);
        gemm_k<true, true><<<g, 256, 0, stream>>>(out_h2, dw1, db1, hmid,
            N_NODES, OUT_D, HID_D, 0, 0);
    }
    {
        dim3 g((IN_D + BN - 1) / BN, (N_NODES + BM - 1) / BM, 1);
        gemm_k<true, true><<<g, 256, 0, stream>>>(hmid, dw2, db2, out_h3,
            N_NODES, HID_D, IN_D, 0, 0);
    }
}

// Round 3
// 572.032 us; speedup vs baseline: 2.0293x; 1.2576x over previous
//
#include <hip/hip_runtime.h>
#include <hip/hip_bf16.h>

static constexpr int N_NODES = 50000;
static constexpr int N_EDGE  = 1000000;
static constexpr int IN_D    = 256;
static constexpr int HID_D   = 128;
static constexpr int OUT_D   = 64;
static constexpr int R_REL   = 2;

typedef __attribute__((ext_vector_type(8))) short short8;   // 8 bf16 = 4 VGPRs
typedef __attribute__((ext_vector_type(4))) float float4v;

static __device__ __forceinline__ unsigned short f2bf(float v) {
    __hip_bfloat16 h = __float2bfloat16(v);
    return *(unsigned short*)&h;
}

// ---------------- fp32 -> bf16 bulk convert (4 elems/thread) -------------------
__global__ __launch_bounds__(256) void cvt_bf16_k(
    const float* __restrict__ x, unsigned short* __restrict__ y, long n)
{
    const long i = ((long)blockIdx.x * 256 + threadIdx.x) * 4;
    if (i >= n) return;
    const float4 v = *(const float4*)(x + i);
    ushort4 o;
    o.x = f2bf(v.x); o.y = f2bf(v.y); o.z = f2bf(v.z); o.w = f2bf(v.w);
    *(ushort4*)(y + i) = o;
}

// ---- weight prep: W[r][k][o] (fp32) -> Wt[n][k] bf16, n = r*Dout + o ----------
__global__ __launch_bounds__(256) void wprep_k(
    const float* __restrict__ W, unsigned short* __restrict__ Wt, int K, int Dout)
{
    const int idx = blockIdx.x * 256 + threadIdx.x;
    if (idx >= R_REL * Dout * K) return;
    const int n = idx / K, kk = idx % K;
    const int r = n / Dout, o = n % Dout;
    Wt[(long)n * K + kk] = f2bf(W[((long)r * K + kk) * Dout + o]);
}

// ---------------- bf16 MFMA GEMM: C[M,N] = A[M,K] @ Bt[N,K]^T ------------------
// BM = TM*32 (2 waves in m), BN = 128 (2 waves in n). 16x16x32 bf16 MFMA.
// LDS rows padded to 40 shorts (80 B): 16B-aligned ds_read_b128, bank step 20
// -> only 2-way conflicts (free per m136).
template<int TM>
__global__ __launch_bounds__(256) void gemm_bf16_k(
    const unsigned short* __restrict__ A, const unsigned short* __restrict__ Bt,
    float* __restrict__ C, int M, int K, int Nn)
{
    constexpr int BM = TM * 32;
    constexpr int LDK = 40;
    __shared__ __align__(16) unsigned short As[BM * LDK];
    __shared__ __align__(16) unsigned short Bs[128 * LDK];

    const int tid = threadIdx.x;
    const int wave = tid >> 6, lane = tid & 63;
    const int wm = (wave >> 1) * (TM * 16);
    const int wn = (wave & 1) * 64;
    const int bm = blockIdx.y * BM;
    const int bn = blockIdx.x * 128;
    const int l15 = lane & 15, quad = lane >> 4;

    float4v acc[TM][4];
#pragma unroll
    for (int i = 0; i < TM; ++i)
#pragma unroll
        for (int j = 0; j < 4; ++j) acc[i][j] = (float4v){0.f, 0.f, 0.f, 0.f};

    for (int k0 = 0; k0 < K; k0 += 32) {
        // stage A tile: BM rows x 32 cols, 16B chunks
        for (int c = tid; c < BM * 4; c += 256) {
            const int r = c >> 2, ch = c & 3;
            const int gr = min(bm + r, M - 1);   // clamp: no OOB, dup rows unused
            *(uint4*)&As[r * LDK + ch * 8] =
                *(const uint4*)&A[(long)gr * K + k0 + ch * 8];
        }
        // stage B tile: 128 n-rows x 32 cols
        for (int c = tid; c < 128 * 4; c += 256) {
            const int r = c >> 2, ch = c & 3;
            *(uint4*)&Bs[r * LDK + ch * 8] =
                *(const uint4*)&Bt[(long)(bn + r) * K + k0 + ch * 8];
        }
        __syncthreads();

        short8 bfrag[4];
#pragma unroll
        for (int nt = 0; nt < 4; ++nt)
            bfrag[nt] = *(const short8*)&Bs[(wn + nt * 16 + l15) * LDK + quad * 8];
#pragma unroll
        for (int mt = 0; mt < TM; ++mt) {
            const short8 afrag = *(const short8*)&As[(wm + mt * 16 + l15) * LDK + quad * 8];
#pragma unroll
            for (int nt = 0; nt < 4; ++nt)
                acc[mt][nt] = __builtin_amdgcn_mfma_f32_16x16x32_bf16(
                    afrag, bfrag[nt], acc[mt][nt], 0, 0, 0);
        }
        __syncthreads();
    }

    // C/D layout: col = lane&15, row = quad*4 + reg (m89-verified)
#pragma unroll
    for (int mt = 0; mt < TM; ++mt)
#pragma unroll
        for (int nt = 0; nt < 4; ++nt) {
            const int n = bn + wn + nt * 16 + l15;
#pragma unroll
            for (int rg = 0; rg < 4; ++rg) {
                const int m = bm + wm + mt * 16 + quad * 4 + rg;
                if (m < M) C[(long)m * Nn + n] = acc[mt][nt][rg];
            }
        }
}

// ---------------- fp32 tiled GEMM (decoder only): C = A @ B^T + bias -----------
#define BM32 64
#define BN32 64
#define BK32 16

template<bool BT, bool BIAS>
__global__ __launch_bounds__(256) void gemm_k(
    const float* __restrict__ A, const float* __restrict__ B,
    const float* __restrict__ bias, float* __restrict__ C,
    int M, int K, int Nn)
{
    const int bm = blockIdx.y * BM32;
    const int bn = blockIdx.x * BN32;

    __shared__ float Asm[BK32][BM32 + 4];
    __shared__ float Bsm[BK32][BN32 + 4];

    const int tid = threadIdx.x;
    const int tx = tid & 15;
    const int ty = tid >> 4;

    float acc[4][4] = {};

    for (int k0 = 0; k0 < K; k0 += BK32) {
        {
            const int r = tid >> 2;
            const int c = (tid & 3) << 2;
            float4 v = make_float4(0.f, 0.f, 0.f, 0.f);
            const int m = bm + r;
            if (m < M) v = *(const float4*)(A + (long)m * K + k0 + c);
            Asm[c + 0][r] = v.x; Asm[c + 1][r] = v.y;
            Asm[c + 2][r] = v.z; Asm[c + 3][r] = v.w;
        }
        {
            const int r = tid >> 2;
            const int c = (tid & 3) << 2;
            const int n = bn + r;
            float4 v = make_float4(0.f, 0.f, 0.f, 0.f);
            if (n < Nn) v = *(const float4*)(B + (long)n * K + k0 + c);
            Bsm[c + 0][r] = v.x; Bsm[c + 1][r] = v.y;
            Bsm[c + 2][r] = v.z; Bsm[c + 3][r] = v.w;
        }
        __syncthreads();

#pragma unroll
        for (int k = 0; k < BK32; ++k) {
            const float4 a = *(const float4*)&Asm[k][ty << 2];
            const float4 b = *(const float4*)&Bsm[k][tx << 2];
            acc[0][0] = fmaf(a.x, b.x, acc[0][0]);
            acc[0][1] = fmaf(a.x, b.y, acc[0][1]);
            acc[0][2] = fmaf(a.x, b.z, acc[0][2]);
            acc[0][3] = fmaf(a.x, b.w, acc[0][3]);
            acc[1][0] = fmaf(a.y, b.x, acc[1][0]);
            acc[1][1] = fmaf(a.y, b.y, acc[1][1]);
            acc[1][2] = fmaf(a.y, b.z, acc[1][2]);
            acc[1][3] = fmaf(a.y, b.w, acc[1][3]);
            acc[2][0] = fmaf(a.z, b.x, acc[2][0]);
            acc[2][1] = fmaf(a.z, b.y, acc[2][1]);
            acc[2][2] = fmaf(a.z, b.z, acc[2][2]);
            acc[2][3] = fmaf(a.z, b.w, acc[2][3]);
            acc[3][0] = fmaf(a.w, b.x, acc[3][0]);
            acc[3][1] = fmaf(a.w, b.y, acc[3][1]);
            acc[3][2] = fmaf(a.w, b.z, acc[3][2]);
            acc[3][3] = fmaf(a.w, b.w, acc[3][3]);
        }
        __syncthreads();
    }

#pragma unroll
    for (int mi = 0; mi < 4; ++mi) {
        const int m = bm + (ty << 2) + mi;
        if (m >= M) continue;
        float* crow = C + (long)m * Nn;
#pragma unroll
        for (int ni = 0; ni < 4; ++ni) {
            const int n = bn + (tx << 2) + ni;
            if (n < Nn) {
                float v = acc[mi][ni];
                if (BIAS) v += bias[n];
                crow[n] = v;
            }
        }
    }
}

// ---------------- q/k dots over interleaved proj [node][R*D] -------------------
__global__ __launch_bounds__(256) void dotsI_k(
    const float* __restrict__ proj, const float* __restrict__ q,
    const float* __restrict__ k, float* __restrict__ qd, float* __restrict__ kd,
    int Nn, int D)
{
    const int node = (int)((blockIdx.x * (long)blockDim.x + threadIdx.x) >> 6);
    const int lane = threadIdx.x & 63;
    if (node >= Nn) return;
    const float* row = proj + (long)node * (2 * D);
    float sq0 = 0.f, sk0 = 0.f, sq1 = 0.f, sk1 = 0.f;
    for (int i = lane; i < D; i += 64) {
        const float qi = q[i], ki = k[i];
        const float v0 = row[i], v1 = row[D + i];
        sq0 = fmaf(v0, qi, sq0); sk0 = fmaf(v0, ki, sk0);
        sq1 = fmaf(v1, qi, sq1); sk1 = fmaf(v1, ki, sk1);
    }
#pragma unroll
    for (int off = 32; off; off >>= 1) {
        sq0 += __shfl_xor(sq0, off); sk0 += __shfl_xor(sk0, off);
        sq1 += __shfl_xor(sq1, off); sk1 += __shfl_xor(sk1, off);
    }
    if (lane == 0) {
        qd[node] = sq0; qd[Nn + node] = sq1;
        kd[node] = sk0; kd[Nn + node] = sk1;
    }
}

// ---------------- CSR build ----------------------------------------------------
__global__ __launch_bounds__(256) void hist_k(
    const int* __restrict__ dstv, int* __restrict__ cnt, int E)
{
    const int e = blockIdx.x * blockDim.x + threadIdx.x;
    if (e >= E) return;
    atomicAdd(&cnt[dstv[e]], 1);
}

// two-level scan: per-block exclusive + block sums
__global__ __launch_bounds__(256) void scan1_k(
    const int* __restrict__ cnt, int* __restrict__ excl_out,
    int* __restrict__ bsum, int n)
{
    __shared__ int s[256];
    const int t = threadIdx.x;
    const int i = blockIdx.x * 256 + t;
    const int v = (i < n) ? cnt[i] : 0;
    s[t] = v;
    __syncthreads();
    for (int off = 1; off < 256; off <<= 1) {
        const int x = (t >= off) ? s[t - off] : 0;
        __syncthreads();
        s[t] += x;
        __syncthreads();
    }
    if (i < n) excl_out[i] = s[t] - v;
    if (t == 255) bsum[blockIdx.x] = s[255];
}

__global__ __launch_bounds__(256) void scan2_k(
    int* __restrict__ bsum, int* __restrict__ bpre, int nb)
{
    __shared__ int s[256];
    const int t = threadIdx.x;
    const int v = (t < nb) ? bsum[t] : 0;
    s[t] = v;
    __syncthreads();
    for (int off = 1; off < 256; off <<= 1) {
        const int x = (t >= off) ? s[t - off] : 0;
        __syncthreads();
        s[t] += x;
        __syncthreads();
    }
    if (t < nb) bpre[t] = s[t] - v;
}

__global__ __launch_bounds__(256) void scan3_k(
    int* __restrict__ excl, const int* __restrict__ bpre,
    int* __restrict__ offs, int* __restrict__ cursor, int n, int total)
{
    const int i = blockIdx.x * 256 + threadIdx.x;
    if (i >= n) return;
    const int v = excl[i] + bpre[i >> 8];
    offs[i] = v; cursor[i] = v;
    if (i == 0) offs[n] = total;
}

__global__ __launch_bounds__(256) void scatter_k(
    const int* __restrict__ srcv, const int* __restrict__ dstv,
    const int* __restrict__ et, int* __restrict__ cursor,
    int* __restrict__ spack, int* __restrict__ sperm, int E)
{
    const int e = blockIdx.x * blockDim.x + threadIdx.x;
    if (e >= E) return;
    const int pos = atomicAdd(&cursor[dstv[e]], 1);
    spack[pos] = (et[e] << 16) | srcv[e];
    sperm[pos] = e;
}

// -------- layer-1 fused softmax+aggr+ELU: proj [node][256], out bf16 [node][128]
__global__ __launch_bounds__(256) void aggr1_k(
    const int* __restrict__ offs, const int* __restrict__ spack,
    const int* __restrict__ sperm, const float* __restrict__ qd,
    const float* __restrict__ kd, const float* __restrict__ proj,
    float* __restrict__ att_out, unsigned short* __restrict__ h1b, int Nn)
{
    const int d = blockIdx.x * 4 + (threadIdx.x >> 6);
    const int lane = threadIdx.x & 63;
    if (d >= Nn) return;
    const int beg = offs[d], end = offs[d + 1];
    const float qd0 = qd[d], qd1 = qd[Nn + d];

    float exsum = 0.f;
    for (int b = beg; b < end; b += 64) {
        const int i = b + lane;
        float ex = 0.f;
        if (i < end) {
            const int p = spack[i];
            const int s = p & 0xFFFF, t = p >> 16;
            float a = (t ? qd1 : qd0) + kd[t * Nn + s];
            a = a > 0.f ? a : 0.2f * a;
            ex = expf(a);
        }
#pragma unroll
        for (int off = 32; off; off >>= 1) ex += __shfl_xor(ex, off);
        exsum += ex;
    }
    const float inv = 1.f / (exsum + 1e-16f);

    float acc0 = 0.f, acc1 = 0.f;
    for (int b = beg; b < end; b += 64) {
        const int i = b + lane;
        float av = 0.f; int sp = 0;
        if (i < end) {
            sp = spack[i];
            const int s = sp & 0xFFFF, t = sp >> 16;
            float a = (t ? qd1 : qd0) + kd[t * Nn + s];
            a = a > 0.f ? a : 0.2f * a;
            av = expf(a) * inv;
            att_out[sperm[i]] = av;
        }
        const int cnt = min(64, end - b);
        for (int j = 0; j < cnt; ++j) {
            const float aj = __shfl(av, j);
            const int spj = __shfl(sp, j);
            const int sj = spj & 0xFFFF, tj = spj >> 16;
            const float2 v = *(const float2*)(proj + (long)sj * 256 + tj * 128 + lane * 2);
            acc0 = fmaf(aj, v.x, acc0);
            acc1 = fmaf(aj, v.y, acc1);
        }
    }
    const float v0 = acc0 > 0.f ? acc0 : expm1f(acc0);
    const float v1 = acc1 > 0.f ? acc1 : expm1f(acc1);
    ushort2 st; st.x = f2bf(v0); st.y = f2bf(v1);
    *(ushort2*)&h1b[(long)d * 128 + lane * 2] = st;  // elems (2*lane, 2*lane+1)
}

// -------- layer-2 fused: proj2 [node][128], out fp32 [node][64] ----------------
__global__ __launch_bounds__(256) void aggr2_k(
    const int* __restrict__ offs, const int* __restrict__ spack,
    const int* __restrict__ sperm, const float* __restrict__ qd,
    const float* __restrict__ kd, const float* __restrict__ proj,
    float* __restrict__ att_out, float* __restrict__ out, int Nn)
{
    const int d = blockIdx.x * 4 + (threadIdx.x >> 6);
    const int lane = threadIdx.x & 63;
    if (d >= Nn) return;
    const int beg = offs[d], end = offs[d + 1];
    const float qd0 = qd[d], qd1 = qd[Nn + d];

    float exsum = 0.f;
    for (int b = beg; b < end; b += 64) {
        const int i = b + lane;
        float ex = 0.f;
        if (i < end) {
            const int p = spack[i];
            const int s = p & 0xFFFF, t = p >> 16;
            float a = (t ? qd1 : qd0) + kd[t * Nn + s];
            a = a > 0.f ? a : 0.2f * a;
            ex = expf(a);
        }
#pragma unroll
        for (int off = 32; off; off >>= 1) ex += __shfl_xor(ex, off);
        exsum += ex;
    }
    const float inv = 1.f / (exsum + 1e-16f);

    float acc0 = 0.f;
    for (int b = beg; b < end; b += 64) {
        const int i = b + lane;
        float av = 0.f; int sp = 0;
        if (i < end) {
            sp = spack[i];
            const int s = sp & 0xFFFF, t = sp >> 16;
            float a = (t ? qd1 : qd0) + kd[t * Nn + s];
            a = a > 0.f ? a : 0.2f * a;
            av = expf(a) * inv;
            att_out[sperm[i]] = av;
        }
        const int cnt = min(64, end - b);
        for (int j = 0; j < cnt; ++j) {
            const float aj = __shfl(av, j);
            const int spj = __shfl(sp, j);
            const int sj = spj & 0xFFFF, tj = spj >> 16;
            acc0 = fmaf(aj, proj[(long)sj * 128 + tj * 64 + lane], acc0);
        }
    }
    out[(long)d * 64 + lane] = acc0 > 0.f ? acc0 : expm1f(acc0);
}

extern "C" void kernel_launch(void* const* d_in, const int* in_sizes, int n_in,
                              void* d_out, int out_size, void* d_ws, size_t ws_size,
                              hipStream_t stream)
{
    const float* features = (const float*)d_in[0];
    const int*   eidx     = (const int*)d_in[1];
    const int*   etype    = (const int*)d_in[2];
    const float* W1       = (const float*)d_in[3];
    const float* q1       = (const float*)d_in[4];
    const float* k1       = (const float*)d_in[5];
    const float* W2       = (const float*)d_in[6];
    const float* q2       = (const float*)d_in[7];
    const float* k2       = (const float*)d_in[8];
    const float* dw1      = (const float*)d_in[9];
    const float* db1      = (const float*)d_in[10];
    const float* dw2      = (const float*)d_in[11];
    const float* db2      = (const float*)d_in[12];

    const int* srcv = eidx;
    const int* dstv = eidx + N_EDGE;

    float* out_h2 = (float*)d_out;                  // N x 64
    float* out_h3 = out_h2 + (long)N_NODES * OUT_D; // N x 256
    float* att1   = out_h3 + (long)N_NODES * IN_D;  // E
    float* att2   = att1 + N_EDGE;                  // E

    float* f = (float*)d_ws;
    float* proj1 = f;                               // 12.8M floats [N][256]
    float* proj2 = f;                               // alias: proj1 dead after aggr1
    float* hmid  = f + 6400000;                     // alias: proj2 uses [0,6.4M)
    unsigned short* featb = (unsigned short*)(f + 12800000);  // 12.8M us
    unsigned short* h1b   = featb;                  // alias: featb dead after gemm1
    float* qd1 = f + 19200000;
    float* kd1 = f + 19300000;
    float* qd2 = f + 19400000;
    float* kd2 = f + 19500000;
    int* cnt    = (int*)(f + 19600000);             // 50000
    int* offs   = cnt + 50000;                      // 50001
    int* cursor = offs + 50001;                     // 50000
    int* bsum   = cursor + 50000;                   // 256
    int* bpre   = bsum + 256;                       // 256
    int* excl   = bpre + 256;                       // 50000 (scan temp)
    int* spack  = excl + 50000;                     // 1M
    int* sperm  = spack + N_EDGE;                   // 1M
    unsigned short* Wc1t = (unsigned short*)(sperm + N_EDGE);  // 65536 us
    unsigned short* Wc2t = Wc1t + 65536;                       // 16384 us

    const int NB = (N_NODES + 255) / 256;  // 196 scan blocks

    // ---- prep: bf16 conversions + CSR build ----
    cvt_bf16_k<<<(int)(((long)N_NODES * IN_D / 4 + 255) / 256), 256, 0, stream>>>(
        features, featb, (long)N_NODES * IN_D);
    wprep_k<<<(R_REL * HID_D * IN_D + 255) / 256, 256, 0, stream>>>(W1, Wc1t, IN_D, HID_D);
    wprep_k<<<(R_REL * OUT_D * HID_D + 255) / 256, 256, 0, stream>>>(W2, Wc2t, HID_D, OUT_D);

    hipMemsetAsync(cnt, 0, sizeof(int) * N_NODES, stream);
    hist_k<<<(N_EDGE + 255) / 256, 256, 0, stream>>>(dstv, cnt, N_EDGE);
    scan1_k<<<NB, 256, 0, stream>>>(cnt, excl, bsum, N_NODES);
    scan2_k<<<1, 256, 0, stream>>>(bsum, bpre, NB);
    scan3_k<<<NB, 256, 0, stream>>>(excl, bpre, offs, cursor, N_NODES, N_EDGE);
    scatter_k<<<(N_EDGE + 255) / 256, 256, 0, stream>>>(
        srcv, dstv, etype, cursor, spack, sperm, N_EDGE);

    // ---- layer 1: proj1[n][r*128+o] = feats @ [W1_0|W1_1] (bf16 MFMA) ----
    gemm_bf16_k<4><<<dim3(2, (N_NODES + 127) / 128), 256, 0, stream>>>(
        featb, Wc1t, proj1, N_NODES, IN_D, 2 * HID_D);
    dotsI_k<<<(int)(((long)N_NODES * 64 + 255) / 256), 256, 0, stream>>>(
        proj1, q1, k1, qd1, kd1, N_NODES, HID_D);
    aggr1_k<<<(N_NODES + 3) / 4, 256, 0, stream>>>(
        offs, spack, sperm, qd1, kd1, proj1, att1, h1b, N_NODES);

    // ---- layer 2: proj2[n][r*64+o] = h1 @ [W2_0|W2_1] (bf16 MFMA) ----
    gemm_bf16_k<2><<<dim3(1, (N_NODES + 63) / 64), 256, 0, stream>>>(
        h1b, Wc2t, proj2, N_NODES, HID_D, 2 * OUT_D);
    dotsI_k<<<(int)(((long)N_NODES * 64 + 255) / 256), 256, 0, stream>>>(
        proj2, q2, k2, qd2, kd2, N_NODES, OUT_D);
    aggr2_k<<<(N_NODES + 3) / 4, 256, 0, stream>>>(
        offs, spack, sperm, qd2, kd2, proj2, att2, out_h2, N_NODES);

    // ---- decoder (fp32 vector GEMM, A @ B^T + bias) ----
    gemm_k<true, true><<<dim3(HID_D / BN32, (N_NODES + BM32 - 1) / BM32), 256, 0, stream>>>(
        out_h2, dw1, db1, hmid, N_NODES, OUT_D, HID_D);
    gemm_k<true, true><<<dim3(IN_D / BN32, (N_NODES + BM32 - 1) / BM32), 256, 0, stream>>>(
        hmid, dw2, db2, out_h3, N_NODES, HID_D, IN_D);
}

// Round 4
// 547.147 us; speedup vs baseline: 2.1216x; 1.0455x over previous
//
#include <hip/hip_runtime.h>
#include <hip/hip_bf16.h>

static constexpr int N_NODES = 50000;
static constexpr int N_EDGE  = 1000000;
static constexpr int IN_D    = 256;
static constexpr int HID_D   = 128;
static constexpr int OUT_D   = 64;
static constexpr int R_REL   = 2;

typedef __attribute__((ext_vector_type(8))) short short8;   // 8 bf16 = 4 VGPRs
typedef __attribute__((ext_vector_type(4))) float float4v;

static __device__ __forceinline__ unsigned short f2bf(float v) {
    __hip_bfloat16 h = __float2bfloat16(v);
    return *(unsigned short*)&h;
}
static __device__ __forceinline__ float bf2f(unsigned short u) {
    union { unsigned int i; float f; } c; c.i = ((unsigned int)u) << 16; return c.f;
}

// ---------------- fp32 -> bf16 bulk convert (4 elems/thread) -------------------
__global__ __launch_bounds__(256) void cvt_bf16_k(
    const float* __restrict__ x, unsigned short* __restrict__ y, long n)
{
    const long i = ((long)blockIdx.x * 256 + threadIdx.x) * 4;
    if (i >= n) return;
    const float4 v = *(const float4*)(x + i);
    ushort4 o;
    o.x = f2bf(v.x); o.y = f2bf(v.y); o.z = f2bf(v.z); o.w = f2bf(v.w);
    *(ushort4*)(y + i) = o;
}

// ---- relation weight prep: W[r][k][o] fp32 -> Wt[n][k] bf16, n = r*Dout+o ----
__global__ __launch_bounds__(256) void wprep_k(
    const float* __restrict__ W, unsigned short* __restrict__ Wt, int K, int Dout)
{
    const int idx = blockIdx.x * 256 + threadIdx.x;
    if (idx >= R_REL * Dout * K) return;
    const int n = idx / K, kk = idx % K;
    const int r = n / Dout, o = n % Dout;
    Wt[(long)n * K + kk] = f2bf(W[((long)r * K + kk) * Dout + o]);
}

// ---- decoder weight split: fp32 -> hi/lo bf16 (same layout) -------------------
__global__ __launch_bounds__(256) void wsplit_k(
    const float* __restrict__ Wsrc, unsigned short* __restrict__ Wh,
    unsigned short* __restrict__ Wl, int n)
{
    const int i = blockIdx.x * 256 + threadIdx.x;
    if (i >= n) return;
    const float v = Wsrc[i];
    const unsigned short hi = f2bf(v);
    Wh[i] = hi;
    Wl[i] = f2bf(v - bf2f(hi));
}

// ---------------- bf16 MFMA GEMM: Cb[M,N] (bf16) = A[M,K] @ Bt[N,K]^T ----------
// LDS rows padded to 40 shorts (80 B): 16B-aligned ds_read_b128, 2-way-only
// bank conflicts (free per m136).
template<int TM>
__global__ __launch_bounds__(256) void gemm_bf16_k(
    const unsigned short* __restrict__ A, const unsigned short* __restrict__ Bt,
    unsigned short* __restrict__ Cb, int M, int K, int Nn)
{
    constexpr int BM = TM * 32;
    constexpr int LDK = 40;
    __shared__ __align__(16) unsigned short As[BM * LDK];
    __shared__ __align__(16) unsigned short Bs[128 * LDK];

    const int tid = threadIdx.x;
    const int wave = tid >> 6, lane = tid & 63;
    const int wm = (wave >> 1) * (TM * 16);
    const int wn = (wave & 1) * 64;
    const int bm = blockIdx.y * BM;
    const int bn = blockIdx.x * 128;
    const int l15 = lane & 15, quad = lane >> 4;

    float4v acc[TM][4];
#pragma unroll
    for (int i = 0; i < TM; ++i)
#pragma unroll
        for (int j = 0; j < 4; ++j) acc[i][j] = (float4v){0.f, 0.f, 0.f, 0.f};

    for (int k0 = 0; k0 < K; k0 += 32) {
        for (int c = tid; c < BM * 4; c += 256) {
            const int r = c >> 2, ch = c & 3;
            const int gr = min(bm + r, M - 1);
            *(uint4*)&As[r * LDK + ch * 8] =
                *(const uint4*)&A[(long)gr * K + k0 + ch * 8];
        }
        for (int c = tid; c < 128 * 4; c += 256) {
            const int r = c >> 2, ch = c & 3;
            *(uint4*)&Bs[r * LDK + ch * 8] =
                *(const uint4*)&Bt[(long)(bn + r) * K + k0 + ch * 8];
        }
        __syncthreads();

        short8 bfrag[4];
#pragma unroll
        for (int nt = 0; nt < 4; ++nt)
            bfrag[nt] = *(const short8*)&Bs[(wn + nt * 16 + l15) * LDK + quad * 8];
#pragma unroll
        for (int mt = 0; mt < TM; ++mt) {
            const short8 afrag = *(const short8*)&As[(wm + mt * 16 + l15) * LDK + quad * 8];
#pragma unroll
            for (int nt = 0; nt < 4; ++nt)
                acc[mt][nt] = __builtin_amdgcn_mfma_f32_16x16x32_bf16(
                    afrag, bfrag[nt], acc[mt][nt], 0, 0, 0);
        }
        __syncthreads();
    }

    // C/D layout: col = lane&15, row = quad*4 + reg (m89-verified)
#pragma unroll
    for (int mt = 0; mt < TM; ++mt)
#pragma unroll
        for (int nt = 0; nt < 4; ++nt) {
            const int n = bn + wn + nt * 16 + l15;
#pragma unroll
            for (int rg = 0; rg < 4; ++rg) {
                const int m = bm + wm + mt * 16 + quad * 4 + rg;
                if (m < M) Cb[(long)m * Nn + n] = f2bf(acc[mt][nt][rg]);
            }
        }
}

// -------- decoder split-bf16 MFMA GEMM: C = (Ah+Al)(Bh+Bl)^T + bias ------------
// 3-term Markidis: AhBh + AlBh + AhBl (residual ~2^-17). SPLITOUT writes hi/lo
// bf16 C (feeds next split GEMM); else fp32 C.
template<int TM, bool SPLITOUT>
__global__ __launch_bounds__(256) void dec_gemm_k(
    const unsigned short* __restrict__ Ah, const unsigned short* __restrict__ Al,
    const unsigned short* __restrict__ Bh, const unsigned short* __restrict__ Bl,
    const float* __restrict__ bias, float* __restrict__ Cf,
    unsigned short* __restrict__ Ch, unsigned short* __restrict__ Cl,
    int M, int K, int Nn)
{
    constexpr int BM = TM * 32;
    constexpr int LDK = 40;
    __shared__ __align__(16) unsigned short Ash[BM * LDK];
    __shared__ __align__(16) unsigned short Asl[BM * LDK];
    __shared__ __align__(16) unsigned short Bsh[128 * LDK];
    __shared__ __align__(16) unsigned short Bsl[128 * LDK];

    const int tid = threadIdx.x;
    const int wave = tid >> 6, lane = tid & 63;
    const int wm = (wave >> 1) * (TM * 16);
    const int wn = (wave & 1) * 64;
    const int bm = blockIdx.y * BM;
    const int bn = blockIdx.x * 128;
    const int l15 = lane & 15, quad = lane >> 4;

    float4v acc[TM][4];
#pragma unroll
    for (int i = 0; i < TM; ++i)
#pragma unroll
        for (int j = 0; j < 4; ++j) acc[i][j] = (float4v){0.f, 0.f, 0.f, 0.f};

    for (int k0 = 0; k0 < K; k0 += 32) {
        for (int c = tid; c < BM * 4; c += 256) {
            const int r = c >> 2, ch = c & 3;
            const int gr = min(bm + r, M - 1);
            *(uint4*)&Ash[r * LDK + ch * 8] =
                *(const uint4*)&Ah[(long)gr * K + k0 + ch * 8];
            *(uint4*)&Asl[r * LDK + ch * 8] =
                *(const uint4*)&Al[(long)gr * K + k0 + ch * 8];
        }
        for (int c = tid; c < 128 * 4; c += 256) {
            const int r = c >> 2, ch = c & 3;
            *(uint4*)&Bsh[r * LDK + ch * 8] =
                *(const uint4*)&Bh[(long)(bn + r) * K + k0 + ch * 8];
            *(uint4*)&Bsl[r * LDK + ch * 8] =
                *(const uint4*)&Bl[(long)(bn + r) * K + k0 + ch * 8];
        }
        __syncthreads();

        short8 bh[4], bl[4];
#pragma unroll
        for (int nt = 0; nt < 4; ++nt) {
            bh[nt] = *(const short8*)&Bsh[(wn + nt * 16 + l15) * LDK + quad * 8];
            bl[nt] = *(const short8*)&Bsl[(wn + nt * 16 + l15) * LDK + quad * 8];
        }
#pragma unroll
        for (int mt = 0; mt < TM; ++mt) {
            const short8 ah = *(const short8*)&Ash[(wm + mt * 16 + l15) * LDK + quad * 8];
            const short8 al = *(const short8*)&Asl[(wm + mt * 16 + l15) * LDK + quad * 8];
#pragma unroll
            for (int nt = 0; nt < 4; ++nt) {
                acc[mt][nt] = __builtin_amdgcn_mfma_f32_16x16x32_bf16(ah, bh[nt], acc[mt][nt], 0, 0, 0);
                acc[mt][nt] = __builtin_amdgcn_mfma_f32_16x16x32_bf16(al, bh[nt], acc[mt][nt], 0, 0, 0);
                acc[mt][nt] = __builtin_amdgcn_mfma_f32_16x16x32_bf16(ah, bl[nt], acc[mt][nt], 0, 0, 0);
            }
        }
        __syncthreads();
    }

#pragma unroll
    for (int mt = 0; mt < TM; ++mt)
#pragma unroll
        for (int nt = 0; nt < 4; ++nt) {
            const int n = bn + wn + nt * 16 + l15;
            const float bv = bias[n];
#pragma unroll
            for (int rg = 0; rg < 4; ++rg) {
                const int m = bm + wm + mt * 16 + quad * 4 + rg;
                if (m >= M) continue;
                const float v = acc[mt][nt][rg] + bv;
                if (SPLITOUT) {
                    const unsigned short hi = f2bf(v);
                    Ch[(long)m * Nn + n] = hi;
                    Cl[(long)m * Nn + n] = f2bf(v - bf2f(hi));
                } else {
                    Cf[(long)m * Nn + n] = v;
                }
            }
        }
}

// ---------------- q/k dots over bf16 proj [node][R*D] --------------------------
template<int D>
__global__ __launch_bounds__(256) void dotsB_k(
    const unsigned short* __restrict__ projb, const float* __restrict__ q,
    const float* __restrict__ k, float* __restrict__ qd, float* __restrict__ kd,
    int Nn)
{
    const int node = (int)((blockIdx.x * (long)blockDim.x + threadIdx.x) >> 6);
    const int lane = threadIdx.x & 63;
    if (node >= Nn) return;
    const unsigned short* row = projb + (long)node * (2 * D);
    float sq0, sk0, sq1, sk1;
    if (D == 128) {
        const ushort2 a = *(const ushort2*)(row + 2 * lane);
        const ushort2 b = *(const ushort2*)(row + 128 + 2 * lane);
        const float q0 = q[2 * lane], q1 = q[2 * lane + 1];
        const float c0 = k[2 * lane], c1 = k[2 * lane + 1];
        const float a0 = bf2f(a.x), a1 = bf2f(a.y);
        const float b0 = bf2f(b.x), b1 = bf2f(b.y);
        sq0 = fmaf(a0, q0, a1 * q1); sk0 = fmaf(a0, c0, a1 * c1);
        sq1 = fmaf(b0, q0, b1 * q1); sk1 = fmaf(b0, c0, b1 * c1);
    } else {
        const float a0 = bf2f(row[lane]), b0 = bf2f(row[64 + lane]);
        const float q0 = q[lane], c0 = k[lane];
        sq0 = a0 * q0; sk0 = a0 * c0;
        sq1 = b0 * q0; sk1 = b0 * c0;
    }
#pragma unroll
    for (int off = 32; off; off >>= 1) {
        sq0 += __shfl_xor(sq0, off); sk0 += __shfl_xor(sk0, off);
        sq1 += __shfl_xor(sq1, off); sk1 += __shfl_xor(sk1, off);
    }
    if (lane == 0) {
        qd[node] = sq0; qd[Nn + node] = sq1;
        kd[node] = sk0; kd[Nn + node] = sk1;
    }
}

// ---------------- CSR build ----------------------------------------------------
__global__ __launch_bounds__(256) void hist_k(
    const int* __restrict__ dstv, int* __restrict__ cnt, int E)
{
    const int e = blockIdx.x * blockDim.x + threadIdx.x;
    if (e >= E) return;
    atomicAdd(&cnt[dstv[e]], 1);
}

__global__ __launch_bounds__(256) void scan1_k(
    const int* __restrict__ cnt, int* __restrict__ excl_out,
    int* __restrict__ bsum, int n)
{
    __shared__ int s[256];
    const int t = threadIdx.x;
    const int i = blockIdx.x * 256 + t;
    const int v = (i < n) ? cnt[i] : 0;
    s[t] = v;
    __syncthreads();
    for (int off = 1; off < 256; off <<= 1) {
        const int x = (t >= off) ? s[t - off] : 0;
        __syncthreads();
        s[t] += x;
        __syncthreads();
    }
    if (i < n) excl_out[i] = s[t] - v;
    if (t == 255) bsum[blockIdx.x] = s[255];
}

__global__ __launch_bounds__(256) void scan2_k(
    int* __restrict__ bsum, int* __restrict__ bpre, int nb)
{
    __shared__ int s[256];
    const int t = threadIdx.x;
    const int v = (t < nb) ? bsum[t] : 0;
    s[t] = v;
    __syncthreads();
    for (int off = 1; off < 256; off <<= 1) {
        const int x = (t >= off) ? s[t - off] : 0;
        __syncthreads();
        s[t] += x;
        __syncthreads();
    }
    if (t < nb) bpre[t] = s[t] - v;
}

__global__ __launch_bounds__(256) void scan3_k(
    int* __restrict__ excl, const int* __restrict__ bpre,
    int* __restrict__ offs, int* __restrict__ cursor, int n, int total)
{
    const int i = blockIdx.x * 256 + threadIdx.x;
    if (i >= n) return;
    const int v = excl[i] + bpre[i >> 8];
    offs[i] = v; cursor[i] = v;
    if (i == 0) offs[n] = total;
}

__global__ __launch_bounds__(256) void scatter_k(
    const int* __restrict__ srcv, const int* __restrict__ dstv,
    const int* __restrict__ et, int* __restrict__ cursor,
    int* __restrict__ spack, int* __restrict__ sperm, int E)
{
    const int e = blockIdx.x * blockDim.x + threadIdx.x;
    if (e >= E) return;
    const int pos = atomicAdd(&cursor[dstv[e]], 1);
    spack[pos] = (et[e] << 16) | srcv[e];
    sperm[pos] = e;
}

// -------- layer-1 fused softmax+aggr+ELU: projb [node][256] bf16 -> h1 bf16 ----
__global__ __launch_bounds__(256) void aggr1_k(
    const int* __restrict__ offs, const int* __restrict__ spack,
    const int* __restrict__ sperm, const float* __restrict__ qd,
    const float* __restrict__ kd, const unsigned short* __restrict__ projb,
    float* __restrict__ att_out, unsigned short* __restrict__ h1b, int Nn)
{
    const int d = blockIdx.x * 4 + (threadIdx.x >> 6);
    const int lane = threadIdx.x & 63;
    if (d >= Nn) return;
    const int beg = offs[d], end = offs[d + 1];
    const float qd0 = qd[d], qd1 = qd[Nn + d];

    float exsum = 0.f;
    for (int b = beg; b < end; b += 64) {
        const int i = b + lane;
        float ex = 0.f;
        if (i < end) {
            const int p = spack[i];
            const int s = p & 0xFFFF, t = p >> 16;
            float a = (t ? qd1 : qd0) + kd[t * Nn + s];
            a = a > 0.f ? a : 0.2f * a;
            ex = expf(a);
        }
#pragma unroll
        for (int off = 32; off; off >>= 1) ex += __shfl_xor(ex, off);
        exsum += ex;
    }
    const float inv = 1.f / (exsum + 1e-16f);

    float acc0 = 0.f, acc1 = 0.f;
    for (int b = beg; b < end; b += 64) {
        const int i = b + lane;
        float av = 0.f; int sp = 0;
        if (i < end) {
            sp = spack[i];
            const int s = sp & 0xFFFF, t = sp >> 16;
            float a = (t ? qd1 : qd0) + kd[t * Nn + s];
            a = a > 0.f ? a : 0.2f * a;
            av = expf(a) * inv;
            att_out[sperm[i]] = av;
        }
        const int cnt = min(64, end - b);
        for (int j = 0; j < cnt; ++j) {
            const float aj = __shfl(av, j);
            const int spj = __shfl(sp, j);
            const int sj = spj & 0xFFFF, tj = spj >> 16;
            const ushort2 uv = *(const ushort2*)(projb + (long)sj * 256 + tj * 128 + lane * 2);
            acc0 = fmaf(aj, bf2f(uv.x), acc0);
            acc1 = fmaf(aj, bf2f(uv.y), acc1);
        }
    }
    const float v0 = acc0 > 0.f ? acc0 : expm1f(acc0);
    const float v1 = acc1 > 0.f ? acc1 : expm1f(acc1);
    ushort2 st; st.x = f2bf(v0); st.y = f2bf(v1);
    *(ushort2*)&h1b[(long)d * 128 + lane * 2] = st;
}

// -------- layer-2 fused: projb2 [node][128] bf16 -> h2 fp32 + hi/lo bf16 -------
__global__ __launch_bounds__(256) void aggr2_k(
    const int* __restrict__ offs, const int* __restrict__ spack,
    const int* __restrict__ sperm, const float* __restrict__ qd,
    const float* __restrict__ kd, const unsigned short* __restrict__ projb,
    float* __restrict__ att_out, float* __restrict__ out,
    unsigned short* __restrict__ h2h, unsigned short* __restrict__ h2l, int Nn)
{
    const int d = blockIdx.x * 4 + (threadIdx.x >> 6);
    const int lane = threadIdx.x & 63;
    if (d >= Nn) return;
    const int beg = offs[d], end = offs[d + 1];
    const float qd0 = qd[d], qd1 = qd[Nn + d];

    float exsum = 0.f;
    for (int b = beg; b < end; b += 64) {
        const int i = b + lane;
        float ex = 0.f;
        if (i < end) {
            const int p = spack[i];
            const int s = p & 0xFFFF, t = p >> 16;
            float a = (t ? qd1 : qd0) + kd[t * Nn + s];
            a = a > 0.f ? a : 0.2f * a;
            ex = expf(a);
        }
#pragma unroll
        for (int off = 32; off; off >>= 1) ex += __shfl_xor(ex, off);
        exsum += ex;
    }
    const float inv = 1.f / (exsum + 1e-16f);

    float acc0 = 0.f;
    for (int b = beg; b < end; b += 64) {
        const int i = b + lane;
        float av = 0.f; int sp = 0;
        if (i < end) {
            sp = spack[i];
            const int s = sp & 0xFFFF, t = sp >> 16;
            float a = (t ? qd1 : qd0) + kd[t * Nn + s];
            a = a > 0.f ? a : 0.2f * a;
            av = expf(a) * inv;
            att_out[sperm[i]] = av;
        }
        const int cnt = min(64, end - b);
        for (int j = 0; j < cnt; ++j) {
            const float aj = __shfl(av, j);
            const int spj = __shfl(sp, j);
            const int sj = spj & 0xFFFF, tj = spj >> 16;
            acc0 = fmaf(aj, bf2f(projb[(long)sj * 128 + tj * 64 + lane]), acc0);
        }
    }
    const float v = acc0 > 0.f ? acc0 : expm1f(acc0);
    out[(long)d * 64 + lane] = v;
    const unsigned short hi = f2bf(v);
    h2h[(long)d * 64 + lane] = hi;
    h2l[(long)d * 64 + lane] = f2bf(v - bf2f(hi));
}

extern "C" void kernel_launch(void* const* d_in, const int* in_sizes, int n_in,
                              void* d_out, int out_size, void* d_ws, size_t ws_size,
                              hipStream_t stream)
{
    const float* features = (const float*)d_in[0];
    const int*   eidx     = (const int*)d_in[1];
    const int*   etype    = (const int*)d_in[2];
    const float* W1       = (const float*)d_in[3];
    const float* q1       = (const float*)d_in[4];
    const float* k1       = (const float*)d_in[5];
    const float* W2       = (const float*)d_in[6];
    const float* q2       = (const float*)d_in[7];
    const float* k2       = (const float*)d_in[8];
    const float* dw1      = (const float*)d_in[9];
    const float* db1      = (const float*)d_in[10];
    const float* dw2      = (const float*)d_in[11];
    const float* db2      = (const float*)d_in[12];

    const int* srcv = eidx;
    const int* dstv = eidx + N_EDGE;

    float* out_h2 = (float*)d_out;                  // N x 64
    float* out_h3 = out_h2 + (long)N_NODES * OUT_D; // N x 256
    float* att1   = out_h3 + (long)N_NODES * IN_D;  // E
    float* att2   = att1 + N_EDGE;                  // E

    // ---- workspace carve-up (byte offsets; aggressive temporal aliasing) ----
    char* W = (char*)d_ws;
    unsigned short* projb1 = (unsigned short*)(W);             // [0, 25.6M)
    unsigned short* projb2 = (unsigned short*)(W);             // alias, dead before hid
    unsigned short* hidh   = (unsigned short*)(W);             // [0, 12.8M) after aggr2
    unsigned short* hidl   = (unsigned short*)(W + 12800000);  // [12.8M, 25.6M)
    unsigned short* featb  = (unsigned short*)(W + 25600000);  // [25.6M, 51.2M)
    unsigned short* h1b    = featb;                            // alias after gemm1
    unsigned short* h2h    = (unsigned short*)(W + 25600000 + 12800000);
    unsigned short* h2l    = (unsigned short*)(W + 25600000 + 19200000);
    float* qd1 = (float*)(W + 51200000);
    float* kd1 = qd1 + 2 * N_NODES;
    float* qd2 = kd1 + 2 * N_NODES;
    float* kd2 = qd2 + 2 * N_NODES;
    int* cnt    = (int*)(kd2 + 2 * N_NODES);
    int* offs   = cnt + N_NODES;
    int* cursor = offs + N_NODES + 1;
    int* bsum   = cursor + N_NODES;
    int* bpre   = bsum + 256;
    int* excl   = bpre + 256;
    int* spack  = excl + N_NODES;
    int* sperm  = spack + N_EDGE;
    unsigned short* Wc1t = (unsigned short*)(sperm + N_EDGE);  // 65536
    unsigned short* Wc2t = Wc1t + 65536;                       // 16384
    unsigned short* dw1h = Wc2t + 16384;                       // 8192
    unsigned short* dw1l = dw1h + 8192;
    unsigned short* dw2h = dw1l + 8192;                        // 32768
    unsigned short* dw2l = dw2h + 32768;

    const int NB = (N_NODES + 255) / 256;

    // ---- prep: conversions + CSR build ----
    cvt_bf16_k<<<(int)(((long)N_NODES * IN_D / 4 + 255) / 256), 256, 0, stream>>>(
        features, featb, (long)N_NODES * IN_D);
    wprep_k<<<(R_REL * HID_D * IN_D + 255) / 256, 256, 0, stream>>>(W1, Wc1t, IN_D, HID_D);
    wprep_k<<<(R_REL * OUT_D * HID_D + 255) / 256, 256, 0, stream>>>(W2, Wc2t, HID_D, OUT_D);
    wsplit_k<<<(HID_D * OUT_D + 255) / 256, 256, 0, stream>>>(dw1, dw1h, dw1l, HID_D * OUT_D);
    wsplit_k<<<(IN_D * HID_D + 255) / 256, 256, 0, stream>>>(dw2, dw2h, dw2l, IN_D * HID_D);

    hipMemsetAsync(cnt, 0, sizeof(int) * N_NODES, stream);
    hist_k<<<(N_EDGE + 255) / 256, 256, 0, stream>>>(dstv, cnt, N_EDGE);
    scan1_k<<<NB, 256, 0, stream>>>(cnt, excl, bsum, N_NODES);
    scan2_k<<<1, 256, 0, stream>>>(bsum, bpre, NB);
    scan3_k<<<NB, 256, 0, stream>>>(excl, bpre, offs, cursor, N_NODES, N_EDGE);
    scatter_k<<<(N_EDGE + 255) / 256, 256, 0, stream>>>(
        srcv, dstv, etype, cursor, spack, sperm, N_EDGE);

    // ---- layer 1 ----
    gemm_bf16_k<4><<<dim3(2, (N_NODES + 127) / 128), 256, 0, stream>>>(
        featb, Wc1t, projb1, N_NODES, IN_D, 2 * HID_D);
    dotsB_k<128><<<(int)(((long)N_NODES * 64 + 255) / 256), 256, 0, stream>>>(
        projb1, q1, k1, qd1, kd1, N_NODES);
    aggr1_k<<<(N_NODES + 3) / 4, 256, 0, stream>>>(
        offs, spack, sperm, qd1, kd1, projb1, att1, h1b, N_NODES);

    // ---- layer 2 ----
    gemm_bf16_k<4><<<dim3(1, (N_NODES + 127) / 128), 256, 0, stream>>>(
        h1b, Wc2t, projb2, N_NODES, HID_D, 2 * OUT_D);
    dotsB_k<64><<<(int)(((long)N_NODES * 64 + 255) / 256), 256, 0, stream>>>(
        projb2, q2, k2, qd2, kd2, N_NODES);
    aggr2_k<<<(N_NODES + 3) / 4, 256, 0, stream>>>(
        offs, spack, sperm, qd2, kd2, projb2, att2, out_h2, h2h, h2l, N_NODES);

    // ---- decoder (split-bf16 MFMA, fp32-accurate) ----
    dec_gemm_k<4, true><<<dim3(1, (N_NODES + 127) / 128), 256, 0, stream>>>(
        h2h, h2l, dw1h, dw1l, db1, nullptr, hidh, hidl, N_NODES, OUT_D, HID_D);
    dec_gemm_k<4, false><<<dim3(2, (N_NODES + 127) / 128), 256, 0, stream>>>(
        hidh, hidl, dw2h, dw2l, db2, out_h3, nullptr, nullptr, N_NODES, HID_D, IN_D);
}

// Round 6
// 500.384 us; speedup vs baseline: 2.3199x; 1.0935x over previous
//
#include <hip/hip_runtime.h>
#include <hip/hip_bf16.h>

static constexpr int N_NODES = 50000;
static constexpr int N_EDGE  = 1000000;
static constexpr int IN_D    = 256;
static constexpr int HID_D   = 128;
static constexpr int OUT_D   = 64;
static constexpr int R_REL   = 2;

typedef __attribute__((ext_vector_type(8))) short short8;   // 8 bf16 = 4 VGPRs
typedef __attribute__((ext_vector_type(4))) float float4v;

static __device__ __forceinline__ unsigned short f2bf(float v) {
    __hip_bfloat16 h = __float2bfloat16(v);
    return *(unsigned short*)&h;
}
static __device__ __forceinline__ float bf2f(unsigned short u) {
    union { unsigned int i; float f; } c; c.i = ((unsigned int)u) << 16; return c.f;
}

// ---------------- fp32 -> bf16 bulk convert (4 elems/thread) -------------------
__global__ __launch_bounds__(256) void cvt_bf16_k(
    const float* __restrict__ x, unsigned short* __restrict__ y, long n)
{
    const long i = ((long)blockIdx.x * 256 + threadIdx.x) * 4;
    if (i >= n) return;
    const float4 v = *(const float4*)(x + i);
    ushort4 o;
    o.x = f2bf(v.x); o.y = f2bf(v.y); o.z = f2bf(v.z); o.w = f2bf(v.w);
    *(ushort4*)(y + i) = o;
}

// ---- relation weight prep: W[r][k][o] fp32 -> Wt[n][k] bf16, n = r*Dout+o ----
__global__ __launch_bounds__(256) void wprep_k(
    const float* __restrict__ W, unsigned short* __restrict__ Wt, int K, int Dout)
{
    const int idx = blockIdx.x * 256 + threadIdx.x;
    if (idx >= R_REL * Dout * K) return;
    const int n = idx / K, kk = idx % K;
    const int r = n / Dout, o = n % Dout;
    Wt[(long)n * K + kk] = f2bf(W[((long)r * K + kk) * Dout + o]);
}

// ---- decoder weight split: fp32 -> hi/lo bf16 (same layout) -------------------
__global__ __launch_bounds__(256) void wsplit_k(
    const float* __restrict__ Wsrc, unsigned short* __restrict__ Wh,
    unsigned short* __restrict__ Wl, int n)
{
    const int i = blockIdx.x * 256 + threadIdx.x;
    if (i >= n) return;
    const float v = Wsrc[i];
    const unsigned short hi = f2bf(v);
    Wh[i] = hi;
    Wl[i] = f2bf(v - bf2f(hi));
}

// ---------------- bf16 MFMA GEMM: Cb[M,N] (bf16) = A[M,K] @ Bt[N,K]^T ----------
template<int TM>
__global__ __launch_bounds__(256) void gemm_bf16_k(
    const unsigned short* __restrict__ A, const unsigned short* __restrict__ Bt,
    unsigned short* __restrict__ Cb, int M, int K, int Nn)
{
    constexpr int BM = TM * 32;
    constexpr int LDK = 40;   // 80 B rows: 16B-aligned, 2-way-only bank conflicts
    __shared__ __align__(16) unsigned short As[BM * LDK];
    __shared__ __align__(16) unsigned short Bs[128 * LDK];

    const int tid = threadIdx.x;
    const int wave = tid >> 6, lane = tid & 63;
    const int wm = (wave >> 1) * (TM * 16);
    const int wn = (wave & 1) * 64;
    const int bm = blockIdx.y * BM;
    const int bn = blockIdx.x * 128;
    const int l15 = lane & 15, quad = lane >> 4;

    float4v acc[TM][4];
#pragma unroll
    for (int i = 0; i < TM; ++i)
#pragma unroll
        for (int j = 0; j < 4; ++j) acc[i][j] = (float4v){0.f, 0.f, 0.f, 0.f};

    for (int k0 = 0; k0 < K; k0 += 32) {
        for (int c = tid; c < BM * 4; c += 256) {
            const int r = c >> 2, ch = c & 3;
            const int gr = min(bm + r, M - 1);
            *(uint4*)&As[r * LDK + ch * 8] =
                *(const uint4*)&A[(long)gr * K + k0 + ch * 8];
        }
        for (int c = tid; c < 128 * 4; c += 256) {
            const int r = c >> 2, ch = c & 3;
            *(uint4*)&Bs[r * LDK + ch * 8] =
                *(const uint4*)&Bt[(long)(bn + r) * K + k0 + ch * 8];
        }
        __syncthreads();

        short8 bfrag[4];
#pragma unroll
        for (int nt = 0; nt < 4; ++nt)
            bfrag[nt] = *(const short8*)&Bs[(wn + nt * 16 + l15) * LDK + quad * 8];
#pragma unroll
        for (int mt = 0; mt < TM; ++mt) {
            const short8 afrag = *(const short8*)&As[(wm + mt * 16 + l15) * LDK + quad * 8];
#pragma unroll
            for (int nt = 0; nt < 4; ++nt)
                acc[mt][nt] = __builtin_amdgcn_mfma_f32_16x16x32_bf16(
                    afrag, bfrag[nt], acc[mt][nt], 0, 0, 0);
        }
        __syncthreads();
    }

    // C/D layout: col = lane&15, row = quad*4 + reg (m89-verified)
#pragma unroll
    for (int mt = 0; mt < TM; ++mt)
#pragma unroll
        for (int nt = 0; nt < 4; ++nt) {
            const int n = bn + wn + nt * 16 + l15;
#pragma unroll
            for (int rg = 0; rg < 4; ++rg) {
                const int m = bm + wm + mt * 16 + quad * 4 + rg;
                if (m < M) Cb[(long)m * Nn + n] = f2bf(acc[mt][nt][rg]);
            }
        }
}

// -------- decoder split-bf16 MFMA GEMM: C = (Ah+Al)(Bh+Bl)^T + bias ------------
template<int TM, bool SPLITOUT>
__global__ __launch_bounds__(256) void dec_gemm_k(
    const unsigned short* __restrict__ Ah, const unsigned short* __restrict__ Al,
    const unsigned short* __restrict__ Bh, const unsigned short* __restrict__ Bl,
    const float* __restrict__ bias, float* __restrict__ Cf,
    unsigned short* __restrict__ Ch, unsigned short* __restrict__ Cl,
    int M, int K, int Nn)
{
    constexpr int BM = TM * 32;
    constexpr int LDK = 40;
    __shared__ __align__(16) unsigned short Ash[BM * LDK];
    __shared__ __align__(16) unsigned short Asl[BM * LDK];
    __shared__ __align__(16) unsigned short Bsh[128 * LDK];
    __shared__ __align__(16) unsigned short Bsl[128 * LDK];

    const int tid = threadIdx.x;
    const int wave = tid >> 6, lane = tid & 63;
    const int wm = (wave >> 1) * (TM * 16);
    const int wn = (wave & 1) * 64;
    const int bm = blockIdx.y * BM;
    const int bn = blockIdx.x * 128;
    const int l15 = lane & 15, quad = lane >> 4;

    float4v acc[TM][4];
#pragma unroll
    for (int i = 0; i < TM; ++i)
#pragma unroll
        for (int j = 0; j < 4; ++j) acc[i][j] = (float4v){0.f, 0.f, 0.f, 0.f};

    for (int k0 = 0; k0 < K; k0 += 32) {
        for (int c = tid; c < BM * 4; c += 256) {
            const int r = c >> 2, ch = c & 3;
            const int gr = min(bm + r, M - 1);
            *(uint4*)&Ash[r * LDK + ch * 8] =
                *(const uint4*)&Ah[(long)gr * K + k0 + ch * 8];
            *(uint4*)&Asl[r * LDK + ch * 8] =
                *(const uint4*)&Al[(long)gr * K + k0 + ch * 8];
        }
        for (int c = tid; c < 128 * 4; c += 256) {
            const int r = c >> 2, ch = c & 3;
            *(uint4*)&Bsh[r * LDK + ch * 8] =
                *(const uint4*)&Bh[(long)(bn + r) * K + k0 + ch * 8];
            *(uint4*)&Bsl[r * LDK + ch * 8] =
                *(const uint4*)&Bl[(long)(bn + r) * K + k0 + ch * 8];
        }
        __syncthreads();

        short8 bh[4], bl[4];
#pragma unroll
        for (int nt = 0; nt < 4; ++nt) {
            bh[nt] = *(const short8*)&Bsh[(wn + nt * 16 + l15) * LDK + quad * 8];
            bl[nt] = *(const short8*)&Bsl[(wn + nt * 16 + l15) * LDK + quad * 8];
        }
#pragma unroll
        for (int mt = 0; mt < TM; ++mt) {
            const short8 ah = *(const short8*)&Ash[(wm + mt * 16 + l15) * LDK + quad * 8];
            const short8 al = *(const short8*)&Asl[(wm + mt * 16 + l15) * LDK + quad * 8];
#pragma unroll
            for (int nt = 0; nt < 4; ++nt) {
                acc[mt][nt] = __builtin_amdgcn_mfma_f32_16x16x32_bf16(ah, bh[nt], acc[mt][nt], 0, 0, 0);
                acc[mt][nt] = __builtin_amdgcn_mfma_f32_16x16x32_bf16(al, bh[nt], acc[mt][nt], 0, 0, 0);
                acc[mt][nt] = __builtin_amdgcn_mfma_f32_16x16x32_bf16(ah, bl[nt], acc[mt][nt], 0, 0, 0);
            }
        }
        __syncthreads();
    }

#pragma unroll
    for (int mt = 0; mt < TM; ++mt)
#pragma unroll
        for (int nt = 0; nt < 4; ++nt) {
            const int n = bn + wn + nt * 16 + l15;
            const float bv = bias[n];
#pragma unroll
            for (int rg = 0; rg < 4; ++rg) {
                const int m = bm + wm + mt * 16 + quad * 4 + rg;
                if (m >= M) continue;
                const float v = acc[mt][nt][rg] + bv;
                if (SPLITOUT) {
                    const unsigned short hi = f2bf(v);
                    Ch[(long)m * Nn + n] = hi;
                    Cl[(long)m * Nn + n] = f2bf(v - bf2f(hi));
                } else {
                    Cf[(long)m * Nn + n] = v;
                }
            }
        }
}

// ---------------- q/k dots over bf16 proj [node][R*D] --------------------------
template<int D>
__global__ __launch_bounds__(256) void dotsB_k(
    const unsigned short* __restrict__ projb, const float* __restrict__ q,
    const float* __restrict__ k, float* __restrict__ qd, float* __restrict__ kd,
    int Nn)
{
    const int node = (int)((blockIdx.x * (long)blockDim.x + threadIdx.x) >> 6);
    const int lane = threadIdx.x & 63;
    if (node >= Nn) return;
    const unsigned short* row = projb + (long)node * (2 * D);
    float sq0, sk0, sq1, sk1;
    if (D == 128) {
        const ushort2 a = *(const ushort2*)(row + 2 * lane);
        const ushort2 b = *(const ushort2*)(row + 128 + 2 * lane);
        const float q0 = q[2 * lane], q1 = q[2 * lane + 1];
        const float c0 = k[2 * lane], c1 = k[2 * lane + 1];
        const float a0 = bf2f(a.x), a1 = bf2f(a.y);
        const float b0 = bf2f(b.x), b1 = bf2f(b.y);
        sq0 = fmaf(a0, q0, a1 * q1); sk0 = fmaf(a0, c0, a1 * c1);
        sq1 = fmaf(b0, q0, b1 * q1); sk1 = fmaf(b0, c0, b1 * c1);
    } else {
        const float a0 = bf2f(row[lane]), b0 = bf2f(row[64 + lane]);
        const float q0 = q[lane], c0 = k[lane];
        sq0 = a0 * q0; sk0 = a0 * c0;
        sq1 = b0 * q0; sk1 = b0 * c0;
    }
#pragma unroll
    for (int off = 32; off; off >>= 1) {
        sq0 += __shfl_xor(sq0, off); sk0 += __shfl_xor(sk0, off);
        sq1 += __shfl_xor(sq1, off); sk1 += __shfl_xor(sk1, off);
    }
    if (lane == 0) {
        qd[node] = sq0; qd[Nn + node] = sq1;
        kd[node] = sk0; kd[Nn + node] = sk1;
    }
}

// ---------------- CSR build (rank/scan/place — no atomic->scatter chain) -------
__global__ __launch_bounds__(256) void rank_k(
    const int* __restrict__ dstv, int* __restrict__ cnt,
    int* __restrict__ rank, int E)
{
    const int e = blockIdx.x * blockDim.x + threadIdx.x;
    if (e >= E) return;
    rank[e] = atomicAdd(&cnt[dstv[e]], 1);
}

__global__ __launch_bounds__(256) void scan1_k(
    const int* __restrict__ cnt, int* __restrict__ excl_out,
    int* __restrict__ bsum, int n)
{
    __shared__ int s[256];
    const int t = threadIdx.x;
    const int i = blockIdx.x * 256 + t;
    const int v = (i < n) ? cnt[i] : 0;
    s[t] = v;
    __syncthreads();
    for (int off = 1; off < 256; off <<= 1) {
        const int x = (t >= off) ? s[t - off] : 0;
        __syncthreads();
        s[t] += x;
        __syncthreads();
    }
    if (i < n) excl_out[i] = s[t] - v;
    if (t == 255) bsum[blockIdx.x] = s[255];
}

__global__ __launch_bounds__(256) void scan2_k(
    int* __restrict__ bsum, int* __restrict__ bpre, int nb)
{
    __shared__ int s[256];
    const int t = threadIdx.x;
    const int v = (t < nb) ? bsum[t] : 0;
    s[t] = v;
    __syncthreads();
    for (int off = 1; off < 256; off <<= 1) {
        const int x = (t >= off) ? s[t - off] : 0;
        __syncthreads();
        s[t] += x;
        __syncthreads();
    }
    if (t < nb) bpre[t] = s[t] - v;
}

__global__ __launch_bounds__(256) void scan3_k(
    int* __restrict__ excl, const int* __restrict__ bpre,
    int* __restrict__ offs, int n, int total)
{
    const int i = blockIdx.x * 256 + threadIdx.x;
    if (i >= n) return;
    offs[i] = excl[i] + bpre[i >> 8];
    if (i == 0) offs[n] = total;
}

// place_k: deterministic position, single 8B record write, no atomics.
__global__ __launch_bounds__(256) void place_k(
    const int* __restrict__ srcv, const int* __restrict__ dstv,
    const int* __restrict__ et, const int* __restrict__ rank,
    const int* __restrict__ offs, uint2* __restrict__ recs, int E)
{
    const int e = blockIdx.x * blockDim.x + threadIdx.x;
    if (e >= E) return;
    const int pos = offs[dstv[e]] + rank[e];
    recs[pos] = make_uint2((unsigned)((et[e] << 16) | srcv[e]), (unsigned)e);
}

// -------- layer-1 fused softmax+aggr+ELU: projb [node][256] bf16 -> h1 bf16 ----
__global__ __launch_bounds__(256) void aggr1_k(
    const int* __restrict__ offs, const uint2* __restrict__ recs,
    const float* __restrict__ qd, const float* __restrict__ kd,
    const unsigned short* __restrict__ projb,
    float* __restrict__ att_out, unsigned short* __restrict__ h1b, int Nn)
{
    const int d = blockIdx.x * 4 + (threadIdx.x >> 6);
    const int lane = threadIdx.x & 63;
    if (d >= Nn) return;
    const int beg = offs[d], end = offs[d + 1];
    const float qd0 = qd[d], qd1 = qd[Nn + d];

    float exsum = 0.f;
    for (int b = beg; b < end; b += 64) {
        const int i = b + lane;
        float ex = 0.f;
        if (i < end) {
            const unsigned p = recs[i].x;
            const int s = (int)(p & 0xFFFFu), t = (int)(p >> 16);  // logical shift
            float a = (t ? qd1 : qd0) + kd[t * Nn + s];
            a = a > 0.f ? a : 0.2f * a;
            ex = expf(a);
        }
#pragma unroll
        for (int off = 32; off; off >>= 1) ex += __shfl_xor(ex, off);
        exsum += ex;
    }
    const float inv = 1.f / (exsum + 1e-16f);

    float acc0 = 0.f, acc1 = 0.f;
    for (int b = beg; b < end; b += 64) {
        const int i = b + lane;
        float av = 0.f; unsigned sp = 0;
        if (i < end) {
            const uint2 r = recs[i];
            sp = r.x;
            const int s = (int)(sp & 0xFFFFu), t = (int)(sp >> 16);
            float a = (t ? qd1 : qd0) + kd[t * Nn + s];
            a = a > 0.f ? a : 0.2f * a;
            av = expf(a) * inv;
            att_out[r.y] = av;
        }
        const int cnt = min(64, end - b);
        for (int j = 0; j < cnt; ++j) {
            const float aj = __shfl(av, j);
            const unsigned spj = (unsigned)__shfl((int)sp, j);
            const int sj = (int)(spj & 0xFFFFu), tj = (int)(spj >> 16);
            const ushort2 uv = *(const ushort2*)(projb + (long)sj * 256 + tj * 128 + lane * 2);
            acc0 = fmaf(aj, bf2f(uv.x), acc0);
            acc1 = fmaf(aj, bf2f(uv.y), acc1);
        }
    }
    const float v0 = acc0 > 0.f ? acc0 : expm1f(acc0);
    const float v1 = acc1 > 0.f ? acc1 : expm1f(acc1);
    ushort2 st; st.x = f2bf(v0); st.y = f2bf(v1);
    *(ushort2*)&h1b[(long)d * 128 + lane * 2] = st;
}

// -------- layer-2 fused: projb2 [node][128] bf16 -> h2 fp32 + hi/lo bf16 -------
__global__ __launch_bounds__(256) void aggr2_k(
    const int* __restrict__ offs, const uint2* __restrict__ recs,
    const float* __restrict__ qd, const float* __restrict__ kd,
    const unsigned short* __restrict__ projb,
    float* __restrict__ att_out, float* __restrict__ out,
    unsigned short* __restrict__ h2h, unsigned short* __restrict__ h2l, int Nn)
{
    const int d = blockIdx.x * 4 + (threadIdx.x >> 6);
    const int lane = threadIdx.x & 63;
    if (d >= Nn) return;
    const int beg = offs[d], end = offs[d + 1];
    const float qd0 = qd[d], qd1 = qd[Nn + d];

    float exsum = 0.f;
    for (int b = beg; b < end; b += 64) {
        const int i = b + lane;
        float ex = 0.f;
        if (i < end) {
            const unsigned p = recs[i].x;
            const int s = (int)(p & 0xFFFFu), t = (int)(p >> 16);
            float a = (t ? qd1 : qd0) + kd[t * Nn + s];
            a = a > 0.f ? a : 0.2f * a;
            ex = expf(a);
        }
#pragma unroll
        for (int off = 32; off; off >>= 1) ex += __shfl_xor(ex, off);
        exsum += ex;
    }
    const float inv = 1.f / (exsum + 1e-16f);

    float acc0 = 0.f;
    for (int b = beg; b < end; b += 64) {
        const int i = b + lane;
        float av = 0.f; unsigned sp = 0;
        if (i < end) {
            const uint2 r = recs[i];
            sp = r.x;
            const int s = (int)(sp & 0xFFFFu), t = (int)(sp >> 16);
            float a = (t ? qd1 : qd0) + kd[t * Nn + s];
            a = a > 0.f ? a : 0.2f * a;
            av = expf(a) * inv;
            att_out[r.y] = av;
        }
        const int cnt = min(64, end - b);
        for (int j = 0; j < cnt; ++j) {
            const float aj = __shfl(av, j);
            const unsigned spj = (unsigned)__shfl((int)sp, j);
            const int sj = (int)(spj & 0xFFFFu), tj = (int)(spj >> 16);
            acc0 = fmaf(aj, bf2f(projb[(long)sj * 128 + tj * 64 + lane]), acc0);
        }
    }
    const float v = acc0 > 0.f ? acc0 : expm1f(acc0);
    out[(long)d * 64 + lane] = v;
    const unsigned short hi = f2bf(v);
    h2h[(long)d * 64 + lane] = hi;
    h2l[(long)d * 64 + lane] = f2bf(v - bf2f(hi));
}

extern "C" void kernel_launch(void* const* d_in, const int* in_sizes, int n_in,
                              void* d_out, int out_size, void* d_ws, size_t ws_size,
                              hipStream_t stream)
{
    const float* features = (const float*)d_in[0];
    const int*   eidx     = (const int*)d_in[1];
    const int*   etype    = (const int*)d_in[2];
    const float* W1       = (const float*)d_in[3];
    const float* q1       = (const float*)d_in[4];
    const float* k1       = (const float*)d_in[5];
    const float* W2       = (const float*)d_in[6];
    const float* q2       = (const float*)d_in[7];
    const float* k2       = (const float*)d_in[8];
    const float* dw1      = (const float*)d_in[9];
    const float* db1      = (const float*)d_in[10];
    const float* dw2      = (const float*)d_in[11];
    const float* db2      = (const float*)d_in[12];

    const int* srcv = eidx;
    const int* dstv = eidx + N_EDGE;

    float* out_h2 = (float*)d_out;                  // N x 64
    float* out_h3 = out_h2 + (long)N_NODES * OUT_D; // N x 256
    float* att1   = out_h3 + (long)N_NODES * IN_D;  // E
    float* att2   = att1 + N_EDGE;                  // E

    // ---- workspace carve-up ----
    // Liveness: rank aliases projb1's first 4 MB — rank dies at place_k, and
    // projb1 is first written by gemm_bf16_k which launches AFTER place_k.
    // (Round-5 crash: rank at 53.3M overlapped excl [53.20M,53.40M) — scan1
    // corrupted rank -> place_k scattered OOB -> poison recs -> wild negative
    // index in aggr -> GPU fault.)
    char* W = (char*)d_ws;
    int* rank = (int*)W;                                       // [0, 4M)  (aliases projb1)
    unsigned short* projb1 = (unsigned short*)(W);             // [0, 25.6M)
    unsigned short* projb2 = (unsigned short*)(W);             // alias
    unsigned short* hidh   = (unsigned short*)(W);             // [0, 12.8M) after aggr2
    unsigned short* hidl   = (unsigned short*)(W + 12800000);
    unsigned short* featb  = (unsigned short*)(W + 25600000);  // [25.6M, 51.2M)
    unsigned short* h1b    = featb;                            // alias after gemm1
    unsigned short* h2h    = (unsigned short*)(W + 25600000 + 12800000);
    unsigned short* h2l    = (unsigned short*)(W + 25600000 + 19200000);
    float* qd1 = (float*)(W + 51200000);
    float* kd1 = qd1 + 2 * N_NODES;
    float* qd2 = kd1 + 2 * N_NODES;
    float* kd2 = qd2 + 2 * N_NODES;
    int* cnt    = (int*)(kd2 + 2 * N_NODES);        // ends 53.0M
    int* offs   = cnt + N_NODES;                    // ends 53.200M
    int* bsum   = offs + N_NODES + 1;
    int* bpre   = bsum + 256;
    int* excl   = bpre + 256;                       // ends 53.402M
    uint2* recs = (uint2*)(W + 57300000);           // [57.3M, 65.3M), 8-aligned
    unsigned short* Wc1t = (unsigned short*)(W + 65300000);    // 65536 us
    unsigned short* Wc2t = Wc1t + 65536;                       // 16384 us
    unsigned short* dw1h = Wc2t + 16384;                       // 8192
    unsigned short* dw1l = dw1h + 8192;
    unsigned short* dw2h = dw1l + 8192;                        // 32768
    unsigned short* dw2l = dw2h + 32768;

    const int NB = (N_NODES + 255) / 256;

    // ---- prep: conversions + CSR build ----
    cvt_bf16_k<<<(int)(((long)N_NODES * IN_D / 4 + 255) / 256), 256, 0, stream>>>(
        features, featb, (long)N_NODES * IN_D);
    wprep_k<<<(R_REL * HID_D * IN_D + 255) / 256, 256, 0, stream>>>(W1, Wc1t, IN_D, HID_D);
    wprep_k<<<(R_REL * OUT_D * HID_D + 255) / 256, 256, 0, stream>>>(W2, Wc2t, HID_D, OUT_D);
    wsplit_k<<<(HID_D * OUT_D + 255) / 256, 256, 0, stream>>>(dw1, dw1h, dw1l, HID_D * OUT_D);
    wsplit_k<<<(IN_D * HID_D + 255) / 256, 256, 0, stream>>>(dw2, dw2h, dw2l, IN_D * HID_D);

    hipMemsetAsync(cnt, 0, sizeof(int) * N_NODES, stream);
    rank_k<<<(N_EDGE + 255) / 256, 256, 0, stream>>>(dstv, cnt, rank, N_EDGE);
    scan1_k<<<NB, 256, 0, stream>>>(cnt, excl, bsum, N_NODES);
    scan2_k<<<1, 256, 0, stream>>>(bsum, bpre, NB);
    scan3_k<<<NB, 256, 0, stream>>>(excl, bpre, offs, N_NODES, N_EDGE);
    place_k<<<(N_EDGE + 255) / 256, 256, 0, stream>>>(
        srcv, dstv, etype, rank, offs, recs, N_EDGE);

    // ---- layer 1 ----
    gemm_bf16_k<4><<<dim3(2, (N_NODES + 127) / 128), 256, 0, stream>>>(
        featb, Wc1t, projb1, N_NODES, IN_D, 2 * HID_D);
    dotsB_k<128><<<(int)(((long)N_NODES * 64 + 255) / 256), 256, 0, stream>>>(
        projb1, q1, k1, qd1, kd1, N_NODES);
    aggr1_k<<<(N_NODES + 3) / 4, 256, 0, stream>>>(
        offs, recs, qd1, kd1, projb1, att1, h1b, N_NODES);

    // ---- layer 2 ----
    gemm_bf16_k<4><<<dim3(1, (N_NODES + 127) / 128), 256, 0, stream>>>(
        h1b, Wc2t, projb2, N_NODES, HID_D, 2 * OUT_D);
    dotsB_k<64><<<(int)(((long)N_NODES * 64 + 255) / 256), 256, 0, stream>>>(
        projb2, q2, k2, qd2, kd2, N_NODES);
    aggr2_k<<<(N_NODES + 3) / 4, 256, 0, stream>>>(
        offs, recs, qd2, kd2, projb2, att2, out_h2, h2h, h2l, N_NODES);

    // ---- decoder (split-bf16 MFMA, fp32-accurate) ----
    dec_gemm_k<4, true><<<dim3(1, (N_NODES + 127) / 128), 256, 0, stream>>>(
        h2h, h2l, dw1h, dw1l, db1, nullptr, hidh, hidl, N_NODES, OUT_D, HID_D);
    dec_gemm_k<4, false><<<dim3(2, (N_NODES + 127) / 128), 256, 0, stream>>>(
        hidh, hidl, dw2h, dw2l, db2, out_h3, nullptr, nullptr, N_NODES, HID_D, IN_D);
}